// Round 8
// baseline (538.824 us; speedup 1.0000x reference)
//
#include <hip/hip_runtime.h>
#include <hip/hip_bf16.h>

typedef __attribute__((ext_vector_type(4))) float f32x4;
typedef __attribute__((ext_vector_type(8))) short short8;

__device__ inline unsigned short f2bf(float f) {
    union { float f; unsigned int u; } v; v.f = f;
    unsigned int u = v.u;
    return (unsigned short)((u + 0x7fffu + ((u >> 16) & 1u)) >> 16);
}
__device__ inline float bf2f(unsigned short h) {
    union { unsigned int u; float f; } v; v.u = ((unsigned int)h) << 16; return v.f;
}
__device__ inline float bflo(unsigned int p) {
    union { unsigned int u; float f; } v; v.u = p << 16; return v.f;
}
__device__ inline float bfhi(unsigned int p) {
    union { unsigned int u; float f; } v; v.u = p & 0xffff0000u; return v.f;
}
__device__ inline unsigned int packbf(float a, float b) {
    return (unsigned int)f2bf(a) | ((unsigned int)f2bf(b) << 16);
}

#define EPT 4096   // edges per chunk for range-partitioned passes

// ---------------- fp32 -> bf16 cast ----------------

__global__ __launch_bounds__(256) void cast_k(const float* __restrict__ x, unsigned short* __restrict__ y, int n4) {
    int i = blockIdx.x * 256 + threadIdx.x;
    if (i >= n4) return;
    f32x4 v = ((const f32x4*)x)[i];
    uint2 o; o.x = packbf(v[0], v[1]); o.y = packbf(v[2], v[3]);
    ((uint2*)y)[i] = o;
}

// ---------------- degree / CSR build (XCD-range-partitioned) ----------------

__global__ __launch_bounds__(256) void deg_count8_k(const int* __restrict__ dst, int* __restrict__ deg,
                                                    int e, int n, int n8) {
    int r = blockIdx.x & 7;
    int chunk = blockIdx.x >> 3;
    int base = chunk * EPT;
    int lim = base + EPT; if (lim > e) lim = e;
    int lo = r * n8;
    int hi = lo + n8; if (hi > n) hi = n;
    for (int i = base + threadIdx.x; i < lim; i += 256) {
        int d = dst[i];
        if (d >= lo && d < hi) atomicAdd(&deg[d], 1);
    }
}

__global__ __launch_bounds__(256) void partial_k(const int* __restrict__ deg, int* __restrict__ part, int n) {
    __shared__ int sm[256];
    int t = threadIdx.x;
    int base = blockIdx.x * 1024 + t * 4;
    int s = 0;
#pragma unroll
    for (int j = 0; j < 4; ++j) { int idx = base + j; if (idx < n) s += deg[idx]; }
    sm[t] = s;
    __syncthreads();
    for (int off = 128; off > 0; off >>= 1) {
        if (t < off) sm[t] += sm[t + off];
        __syncthreads();
    }
    if (t == 0) part[blockIdx.x] = sm[0];
}

__global__ __launch_bounds__(256) void scanpart_k(int* __restrict__ part, int nb) {
    __shared__ int sm[256];
    int t = threadIdx.x;
    int v = (t < nb) ? part[t] : 0;
    sm[t] = v;
    __syncthreads();
    for (int off = 1; off < 256; off <<= 1) {
        int u = (t >= off) ? sm[t - off] : 0;
        __syncthreads();
        sm[t] += u;
        __syncthreads();
    }
    if (t < nb) part[t] = sm[t] - v;   // exclusive
}

__global__ __launch_bounds__(256) void rowptr_k(const int* __restrict__ deg, const int* __restrict__ part,
                                                int* __restrict__ rowptr, int* __restrict__ cursor,
                                                float* __restrict__ dinv, int n) {
    __shared__ int sm[256];
    int t = threadIdx.x;
    int base = blockIdx.x * 1024 + t * 4;
    int d[4]; int s = 0;
#pragma unroll
    for (int j = 0; j < 4; ++j) { int idx = base + j; d[j] = (idx < n) ? deg[idx] : 0; s += d[j]; }
    sm[t] = s;
    __syncthreads();
    for (int off = 1; off < 256; off <<= 1) {
        int u = (t >= off) ? sm[t - off] : 0;
        __syncthreads();
        sm[t] += u;
        __syncthreads();
    }
    int ex = part[blockIdx.x] + sm[t] - s;
#pragma unroll
    for (int j = 0; j < 4; ++j) {
        int idx = base + j;
        if (idx < n) {
            rowptr[idx] = ex; cursor[idx] = ex;
            dinv[idx] = rsqrtf(fmaxf((float)d[j], 1.0f));
        }
        ex += d[j];
    }
    if (blockIdx.x == gridDim.x - 1 && t == 255) rowptr[n] = part[blockIdx.x] + sm[255];
}

__global__ __launch_bounds__(256) void scatter8_k(const int* __restrict__ src, const int* __restrict__ dst,
                                                  int* __restrict__ cursor, int* __restrict__ csrc,
                                                  int e, int n, int n8) {
    int r = blockIdx.x & 7;
    int chunk = blockIdx.x >> 3;
    int base = chunk * EPT;
    int lim = base + EPT; if (lim > e) lim = e;
    int lo = r * n8;
    int hi = lo + n8; if (hi > n) hi = n;
    for (int i = base + threadIdx.x; i < lim; i += 256) {
        int d = dst[i];
        if (d >= lo && d < hi) {
            int p = atomicAdd(&cursor[d], 1);
            csrc[p] = src[i];
        }
    }
}

// ---------------- SpMM (normalized adjacency), bf16 rows, CSR by dst ----------------

template<bool AFF>
__global__ __launch_bounds__(256) void spmm_bf_k(const unsigned short* __restrict__ x, const int* __restrict__ rowptr,
                                                 const int* __restrict__ csrc, const float* __restrict__ dinv,
                                                 const float* __restrict__ gscale, const float* __restrict__ goff,
                                                 unsigned short* __restrict__ out, int n) {
    int lane = threadIdx.x & 63;
    int wave = threadIdx.x >> 6;
    int node = blockIdx.x * 4 + wave;
    if (node >= n) return;
    int g = lane >> 4;        // edge group 0..3
    int c = lane & 15;        // uint4 column index: bf16 cols c*8 .. c*8+7
    int beg = rowptr[node], end = rowptr[node + 1];
    float acc[8];
    float sw = 0.f;
#pragma unroll
    for (int j = 0; j < 8; ++j) acc[j] = 0.f;

    int i = beg + g;
    for (; i + 12 < end; i += 16) {
        int s0 = csrc[i], s1 = csrc[i + 4], s2 = csrc[i + 8], s3 = csrc[i + 12];
        float w0 = dinv[s0], w1 = dinv[s1], w2 = dinv[s2], w3 = dinv[s3];
        uint4 v0 = ((const uint4*)(x + (size_t)s0 * 128))[c];
        uint4 v1 = ((const uint4*)(x + (size_t)s1 * 128))[c];
        uint4 v2 = ((const uint4*)(x + (size_t)s2 * 128))[c];
        uint4 v3 = ((const uint4*)(x + (size_t)s3 * 128))[c];
        if (AFF) sw += w0 + w1 + w2 + w3;
        acc[0] += w0 * bflo(v0.x); acc[1] += w0 * bfhi(v0.x);
        acc[2] += w0 * bflo(v0.y); acc[3] += w0 * bfhi(v0.y);
        acc[4] += w0 * bflo(v0.z); acc[5] += w0 * bfhi(v0.z);
        acc[6] += w0 * bflo(v0.w); acc[7] += w0 * bfhi(v0.w);
        acc[0] += w1 * bflo(v1.x); acc[1] += w1 * bfhi(v1.x);
        acc[2] += w1 * bflo(v1.y); acc[3] += w1 * bfhi(v1.y);
        acc[4] += w1 * bflo(v1.z); acc[5] += w1 * bfhi(v1.z);
        acc[6] += w1 * bflo(v1.w); acc[7] += w1 * bfhi(v1.w);
        acc[0] += w2 * bflo(v2.x); acc[1] += w2 * bfhi(v2.x);
        acc[2] += w2 * bflo(v2.y); acc[3] += w2 * bfhi(v2.y);
        acc[4] += w2 * bflo(v2.z); acc[5] += w2 * bfhi(v2.z);
        acc[6] += w2 * bflo(v2.w); acc[7] += w2 * bfhi(v2.w);
        acc[0] += w3 * bflo(v3.x); acc[1] += w3 * bfhi(v3.x);
        acc[2] += w3 * bflo(v3.y); acc[3] += w3 * bfhi(v3.y);
        acc[4] += w3 * bflo(v3.z); acc[5] += w3 * bfhi(v3.z);
        acc[6] += w3 * bflo(v3.w); acc[7] += w3 * bfhi(v3.w);
    }
    for (; i < end; i += 4) {
        int s0 = csrc[i];
        float w0 = dinv[s0];
        uint4 v0 = ((const uint4*)(x + (size_t)s0 * 128))[c];
        if (AFF) sw += w0;
        acc[0] += w0 * bflo(v0.x); acc[1] += w0 * bfhi(v0.x);
        acc[2] += w0 * bflo(v0.y); acc[3] += w0 * bfhi(v0.y);
        acc[4] += w0 * bflo(v0.z); acc[5] += w0 * bfhi(v0.z);
        acc[6] += w0 * bflo(v0.w); acc[7] += w0 * bfhi(v0.w);
    }

#pragma unroll
    for (int j = 0; j < 8; ++j) {
        acc[j] += __shfl_xor(acc[j], 16, 64);
        acc[j] += __shfl_xor(acc[j], 32, 64);
    }
    if (AFF) {
        sw += __shfl_xor(sw, 16, 64);
        sw += __shfl_xor(sw, 32, 64);
    }

    float dd = dinv[node];
    if (g == 0) {
        if (AFF) {
            f32x4 sc0 = ((const f32x4*)(gscale + c * 8))[0];
            f32x4 sc1 = ((const f32x4*)(gscale + c * 8))[1];
            f32x4 of0 = ((const f32x4*)(goff + c * 8))[0];
            f32x4 of1 = ((const f32x4*)(goff + c * 8))[1];
#pragma unroll
            for (int j = 0; j < 4; ++j) {
                acc[j] = sc0[j] * acc[j] + of0[j] * sw;
                acc[4 + j] = sc1[j] * acc[4 + j] + of1[j] * sw;
            }
        }
        uint4 o;
        o.x = packbf(acc[0] * dd, acc[1] * dd);
        o.y = packbf(acc[2] * dd, acc[3] * dd);
        o.z = packbf(acc[4] * dd, acc[5] * dd);
        o.w = packbf(acc[6] * dd, acc[7] * dd);
        ((uint4*)(out + (size_t)node * 128))[c] = o;
    }
}

// ---------------- weight packs (all 5 in one launch) ----------------

__device__ inline void pack_one(const float* __restrict__ W, unsigned short* __restrict__ out,
                                int K, int N, int cheb, int id) {
    int total = (K / 32) * (N / 16) * 64;
    if (id >= total) return;
    int lane = id & 63;
    int t2 = id >> 6;
    int nf = N / 16;
    int f = t2 % nf;
    int ks = t2 / nf;
    int col = f * 16 + (lane & 15);
    int kbase = ks * 32 + ((lane >> 4) * 8);
    for (int j = 0; j < 8; ++j) {
        int kg = kbase + j;
        float v;
        if (cheb) {
            int t = kg >> 7, kk = kg & 127;
            float w0 = W[kk * 128 + col], wb = W[16384 + kk * 128 + col], wc = W[32768 + kk * 128 + col];
            v = (t == 0) ? (w0 - wc) : (t == 1) ? (-wb) : (2.0f * wc);
        } else {
            v = W[(size_t)kg * N + col];
        }
        out[(size_t)id * 8 + j] = f2bf(v);
    }
}

__global__ __launch_bounds__(256) void pack_all_k(const float* W1, unsigned short* wp1,
                                                  const float* W2, unsigned short* wp2,
                                                  const float* W3, unsigned short* wp3,
                                                  const float* mw1, unsigned short* wpm1,
                                                  const float* mw2, unsigned short* wpm2) {
    int b = blockIdx.x, t = threadIdx.x;
    if (b < 24)       pack_one(W1, wp1, 384, 128, 1, b * 256 + t);
    else if (b < 48)  pack_one(W2, wp2, 384, 128, 1, (b - 24) * 256 + t);
    else if (b < 72)  pack_one(W3, wp3, 384, 128, 1, (b - 48) * 256 + t);
    else if (b < 80)  pack_one(mw1, wpm1, 128, 128, 0, (b - 72) * 256 + t);
    else              pack_one(mw2, wpm2, 128, 64, 0, (b - 80) * 256 + t);
}

// ---------------- BN coefficients from fused stats ----------------

__global__ __launch_bounds__(128) void bn_coef_k(const float* __restrict__ gsum, const float* __restrict__ gsqs,
                                                 const float* __restrict__ gamma, const float* __restrict__ beta,
                                                 float* __restrict__ gscale, float* __restrict__ goff, float inv_n) {
    int c = threadIdx.x;
    float mu = gsum[c] * inv_n;
    float var = gsqs[c] * inv_n - mu * mu;
    float sc = rsqrtf(var + 1e-5f) * gamma[c];
    gscale[c] = sc;
    goff[c] = beta[c] - mu * sc;
}

// ---------------- MFMA GEMM with LDS-staged A ----------------
// C[n x NF*16] = [s0|s1|s2](bf16) @ Wpack + bias.  KSTEPS fixed at 12 (K=384).
// All A-tiles (3 x 64 rows x 256B = 48KB) staged to LDS up front: 12 independent
// uint4 loads per thread (12KB in flight/wave, ONE latency wait), XOR-swizzled
// ds_write (q ^= row&7 -> conflict-free reads), then the k-loop runs from LDS.
// STATS: per-column sum/sumsq of outputs. AFFA: affine on s0 during staging.

template<int NF, bool RELU, bool RES, bool OUTF32, bool STATS, bool AFFA>
__global__ __launch_bounds__(256) void gemm_k(const unsigned short* __restrict__ s0,
                                              const unsigned short* __restrict__ s1,
                                              const unsigned short* __restrict__ s2,
                                              const unsigned short* __restrict__ wp,
                                              const float* __restrict__ bias,
                                              const unsigned short* __restrict__ resid,
                                              const float* __restrict__ gscale,
                                              const float* __restrict__ goff,
                                              float* __restrict__ gsum, float* __restrict__ gsqs,
                                              void* __restrict__ outv, int n) {
    __shared__ char alds[3 * 64 * 256];   // 48 KiB
    __shared__ float bs[128], bq[128];
    int t = threadIdx.x;
    int lane = t & 63;
    int wave = t >> 6;
    int row0 = blockIdx.x * 64;

    if (STATS && t < 128) { bs[t] = 0.f; bq[t] = 0.f; }

    // ---- stage A: thread t loads chunk (t&15) of rows (t>>4)+{0,16,32,48} of each buffer
    int chunk = t & 15;
    int rbase = t >> 4;
    const unsigned short* bufs[3] = { s0, s1, s2 };
    uint4 ld[12];
#pragma unroll
    for (int b = 0; b < 3; ++b) {
#pragma unroll
        for (int rr = 0; rr < 4; ++rr) {
            int grow = row0 + rbase + rr * 16;
            if (grow >= n) grow = n - 1;
            ld[b * 4 + rr] = *(const uint4*)(bufs[b] + (size_t)grow * 128 + chunk * 8);
        }
    }
    if (AFFA) {   // affine s0's staged chunk (cols chunk*8 .. chunk*8+7)
        f32x4 sc0 = ((const f32x4*)(gscale + chunk * 8))[0];
        f32x4 sc1 = ((const f32x4*)(gscale + chunk * 8))[1];
        f32x4 of0 = ((const f32x4*)(goff + chunk * 8))[0];
        f32x4 of1 = ((const f32x4*)(goff + chunk * 8))[1];
#pragma unroll
        for (int rr = 0; rr < 4; ++rr) {
            uint4 v = ld[rr];
            v.x = packbf(bflo(v.x) * sc0[0] + of0[0], bfhi(v.x) * sc0[1] + of0[1]);
            v.y = packbf(bflo(v.y) * sc0[2] + of0[2], bfhi(v.y) * sc0[3] + of0[3]);
            v.z = packbf(bflo(v.z) * sc1[0] + of1[0], bfhi(v.z) * sc1[1] + of1[1]);
            v.w = packbf(bflo(v.w) * sc1[2] + of1[2], bfhi(v.w) * sc1[3] + of1[3]);
            ld[rr] = v;
        }
    }
#pragma unroll
    for (int b = 0; b < 3; ++b) {
#pragma unroll
        for (int rr = 0; rr < 4; ++rr) {
            int row = rbase + rr * 16;
            int q = chunk ^ (row & 7);
            *(uint4*)(alds + b * 16384 + row * 256 + q * 16) = ld[b * 4 + rr];
        }
    }
    __syncthreads();

    // ---- MFMA k-loop from LDS
    int rowL = wave * 16 + (lane & 15);        // LDS row 0..63
    int rsw = rowL & 7;
    int kgq = lane >> 4;                       // 16B sub-chunk within 64B k-group

    f32x4 acc[NF];
#pragma unroll
    for (int f = 0; f < NF; ++f) acc[f] = (f32x4)(0.0f);

#pragma unroll
    for (int ks = 0; ks < 12; ++ks) {
        int b = ks >> 2;
        int q = (((ks & 3) << 2) + kgq) ^ rsw;
        short8 a = *(const short8*)(alds + b * 16384 + rowL * 256 + q * 16);
#pragma unroll
        for (int f = 0; f < NF; ++f) {
            short8 bb = *(const short8*)(wp + ((size_t)(ks * NF + f) * 512 + lane * 8));
            acc[f] = __builtin_amdgcn_mfma_f32_16x16x32_bf16(a, bb, acc[f], 0, 0, 0);
        }
    }

    // ---- epilogue
    int colb = lane & 15;
    int rowD = row0 + wave * 16 + ((lane >> 4) << 2);
#pragma unroll
    for (int f = 0; f < NF; ++f) {
        int c = f * 16 + colb;
        float bv = bias[c];
        float ls = 0.f, lq = 0.f;
#pragma unroll
        for (int r = 0; r < 4; ++r) {
            int row = rowD + r;
            if (row >= n) continue;
            float v = acc[f][r] + bv;
            if (RELU) v = fmaxf(v, 0.0f);
            if (RES) v += bf2f(resid[(size_t)row * 128 + c]);
            if (STATS) { ls += v; lq += v * v; }
            if (OUTF32) ((float*)outv)[(size_t)row * (NF * 16) + c] = v;
            else        ((unsigned short*)outv)[(size_t)row * (NF * 16) + c] = f2bf(v);
        }
        if (STATS) { atomicAdd(&bs[c], ls); atomicAdd(&bq[c], lq); }
    }

    if (STATS) {
        __syncthreads();
        if (t < 128) {
            atomicAdd(&gsum[t], bs[t]);
            atomicAdd(&gsqs[t], bq[t]);
        }
    }
}

// ---------------- fused MLP: out = relu(x@mw1+mb1)@mw2 + mb2 ----------------

__global__ __launch_bounds__(256) void mlp_fused_k(const unsigned short* __restrict__ x,
                                                   const unsigned short* __restrict__ wp1,
                                                   const float* __restrict__ mb1,
                                                   const unsigned short* __restrict__ wp2,
                                                   const float* __restrict__ mb2,
                                                   float* __restrict__ out, int n) {
    __shared__ unsigned short tlds[64 * 128];   // 16 KiB
    int lane = threadIdx.x & 63;
    int wave = threadIdx.x >> 6;
    int row0 = blockIdx.x * 64 + wave * 16;
    int rowA = row0 + (lane & 15);
    if (rowA >= n) rowA = n - 1;
    int kg = (lane >> 4) * 8;
    int colb = lane & 15;

    f32x4 acc[8];
#pragma unroll
    for (int f = 0; f < 8; ++f) acc[f] = (f32x4)(0.0f);
#pragma unroll
    for (int ks = 0; ks < 4; ++ks) {
        short8 a = *(const short8*)(x + (size_t)rowA * 128 + ks * 32 + kg);
#pragma unroll
        for (int f = 0; f < 8; ++f) {
            short8 b = *(const short8*)(wp1 + ((size_t)(ks * 8 + f) * 512 + lane * 8));
            acc[f] = __builtin_amdgcn_mfma_f32_16x16x32_bf16(a, b, acc[f], 0, 0, 0);
        }
    }
    int lrowD = wave * 16 + ((lane >> 4) << 2);
#pragma unroll
    for (int f = 0; f < 8; ++f) {
        int c = f * 16 + colb;
        float bv = mb1[c];
#pragma unroll
        for (int r = 0; r < 4; ++r) {
            int lrow = lrowD + r;
            float v = fmaxf(acc[f][r] + bv, 0.0f);
            int byte = lrow * 256 + c * 2;
            byte ^= ((lrow & 7) << 4);
            *(unsigned short*)((char*)tlds + byte) = f2bf(v);
        }
    }
    __syncthreads();

    f32x4 acc2[4];
#pragma unroll
    for (int f = 0; f < 4; ++f) acc2[f] = (f32x4)(0.0f);
    int lrowA = wave * 16 + (lane & 15);
#pragma unroll
    for (int ks = 0; ks < 4; ++ks) {
        int byte = lrowA * 256 + (ks * 32 + kg) * 2;
        byte ^= ((lrowA & 7) << 4);
        short8 a = *(const short8*)((const char*)tlds + byte);
#pragma unroll
        for (int f = 0; f < 4; ++f) {
            short8 b = *(const short8*)(wp2 + ((size_t)(ks * 4 + f) * 512 + lane * 8));
            acc2[f] = __builtin_amdgcn_mfma_f32_16x16x32_bf16(a, b, acc2[f], 0, 0, 0);
        }
    }
    int rowD = row0 + ((lane >> 4) << 2);
#pragma unroll
    for (int f = 0; f < 4; ++f) {
        int c = f * 16 + colb;
        float bv = mb2[c];
#pragma unroll
        for (int r = 0; r < 4; ++r) {
            int row = rowD + r;
            if (row >= n) continue;
            out[(size_t)row * 64 + c] = acc2[f][r] + bv;
        }
    }
}

// ---------------- launch ----------------

extern "C" void kernel_launch(void* const* d_in, const int* in_sizes, int n_in,
                              void* d_out, int out_size, void* d_ws, size_t ws_size,
                              hipStream_t stream) {
    const float* feat  = (const float*)d_in[0];
    const int*   src   = (const int*)d_in[1];
    const int*   dst   = (const int*)d_in[2];
    const float* W1    = (const float*)d_in[3];
    const float* b1    = (const float*)d_in[4];
    const float* W2    = (const float*)d_in[5];
    const float* b2    = (const float*)d_in[6];
    const float* W3    = (const float*)d_in[7];
    const float* b3    = (const float*)d_in[8];
    const float* gamma = (const float*)d_in[9];
    const float* beta  = (const float*)d_in[10];
    const float* mw1   = (const float*)d_in[11];
    const float* mb1   = (const float*)d_in[12];
    const float* mw2   = (const float*)d_in[13];
    const float* mb2   = (const float*)d_in[14];
    float* outp = (float*)d_out;

    const int n = in_sizes[0] / 128;
    const int e = in_sizes[1];
    const int n8 = (n + 7) / 8;

    char* w = (char*)d_ws;
    auto alloc = [&](size_t bytes) -> void* {
        void* p = (void*)w;
        w += (bytes + 255) & ~(size_t)255;
        return p;
    };
    unsigned short* featb = (unsigned short*)alloc((size_t)n * 128 * 2);
    unsigned short* buf0  = (unsigned short*)alloc((size_t)n * 128 * 2);
    unsigned short* buf1  = (unsigned short*)alloc((size_t)n * 128 * 2);
    unsigned short* buf2  = (unsigned short*)alloc((size_t)n * 128 * 2);
    unsigned short* buf3  = (unsigned short*)alloc((size_t)n * 128 * 2);
    int*   deg    = (int*)alloc((size_t)n * 4);
    float* dinv   = (float*)alloc((size_t)n * 4);
    int*   rowptr = (int*)alloc((size_t)(n + 1) * 4);
    int*   cursor = (int*)alloc((size_t)n * 4);
    int*   csrc   = (int*)alloc((size_t)e * 4);
    int*   part   = (int*)alloc(256 * 4);
    unsigned short* wp1  = (unsigned short*)alloc(12 * 8 * 512 * 2);
    unsigned short* wp2  = (unsigned short*)alloc(12 * 8 * 512 * 2);
    unsigned short* wp3  = (unsigned short*)alloc(12 * 8 * 512 * 2);
    unsigned short* wpm1 = (unsigned short*)alloc(4 * 8 * 512 * 2);
    unsigned short* wpm2 = (unsigned short*)alloc(4 * 4 * 512 * 2);
    float* gsum   = (float*)alloc(128 * 4);   // adjacent: one 1KB memset covers
    float* gsqs   = (float*)alloc(128 * 4);
    float* gscale = (float*)alloc(128 * 4);
    float* goff   = (float*)alloc(128 * 4);

    const int gGemm = (n + 63) / 64;
    const int gSpmm = (n + 3) / 4;
    const int nb = (n + 1023) / 1024;
    const int gE8 = 8 * ((e + EPT - 1) / EPT);

    // prep
    cast_k<<<(n * 32 + 255) / 256, 256, 0, stream>>>(feat, featb, n * 32);
    hipMemsetAsync(deg, 0, (size_t)n * 4, stream);
    hipMemsetAsync(gsum, 0, 1024, stream);   // gsum+gsqs (256-aligned adjacent)
    deg_count8_k<<<gE8, 256, 0, stream>>>(dst, deg, e, n, n8);
    partial_k<<<nb, 256, 0, stream>>>(deg, part, n);
    scanpart_k<<<1, 256, 0, stream>>>(part, nb);
    rowptr_k<<<nb, 256, 0, stream>>>(deg, part, rowptr, cursor, dinv, n);
    scatter8_k<<<gE8, 256, 0, stream>>>(src, dst, cursor, csrc, e, n, n8);
    pack_all_k<<<84, 256, 0, stream>>>(W1, wp1, W2, wp2, W3, wp3, mw1, wpm1, mw2, wpm2);

    // Layer 1: cheb(features, W1) -> relu -> buf0 (pre-BN), fused BN stats
    spmm_bf_k<false><<<gSpmm, 256, 0, stream>>>(featb, rowptr, csrc, dinv, nullptr, nullptr, buf1, n);
    spmm_bf_k<false><<<gSpmm, 256, 0, stream>>>(buf1, rowptr, csrc, dinv, nullptr, nullptr, buf2, n);
    gemm_k<8, true, false, false, true, false><<<gGemm, 256, 0, stream>>>(
        featb, buf1, buf2, wp1, b1, nullptr, nullptr, nullptr, gsum, gsqs, buf0, n);
    bn_coef_k<<<1, 128, 0, stream>>>(gsum, gsqs, gamma, beta, gscale, goff, 1.0f / (float)n);

    // Layer 2a: cheb(BN(buf0), W2) -> relu -> buf3  (BN fused into consumers)
    spmm_bf_k<true><<<gSpmm, 256, 0, stream>>>(buf0, rowptr, csrc, dinv, gscale, goff, buf1, n);
    spmm_bf_k<false><<<gSpmm, 256, 0, stream>>>(buf1, rowptr, csrc, dinv, nullptr, nullptr, buf2, n);
    gemm_k<8, true, false, false, false, true><<<gGemm, 256, 0, stream>>>(
        buf0, buf1, buf2, wp2, b2, nullptr, gscale, goff, nullptr, nullptr, buf3, n);

    // Layer 2b: cheb(buf3, W2) -> relu -> buf0
    spmm_bf_k<false><<<gSpmm, 256, 0, stream>>>(buf3, rowptr, csrc, dinv, nullptr, nullptr, buf1, n);
    spmm_bf_k<false><<<gSpmm, 256, 0, stream>>>(buf1, rowptr, csrc, dinv, nullptr, nullptr, buf2, n);
    gemm_k<8, true, false, false, false, false><<<gGemm, 256, 0, stream>>>(
        buf3, buf1, buf2, wp2, b2, nullptr, nullptr, nullptr, nullptr, nullptr, buf0, n);

    // Layer 3: cheb(buf0, W3) -> relu -> + residual(buf0) -> buf3
    spmm_bf_k<false><<<gSpmm, 256, 0, stream>>>(buf0, rowptr, csrc, dinv, nullptr, nullptr, buf1, n);
    spmm_bf_k<false><<<gSpmm, 256, 0, stream>>>(buf1, rowptr, csrc, dinv, nullptr, nullptr, buf2, n);
    gemm_k<8, true, true, false, false, false><<<gGemm, 256, 0, stream>>>(
        buf0, buf1, buf2, wp3, b3, buf0, nullptr, nullptr, nullptr, nullptr, buf3, n);

    // fused MLP
    mlp_fused_k<<<gGemm, 256, 0, stream>>>(buf3, wpm1, mb1, wpm2, mb2, outp, n);
}

// Round 9
// 491.677 us; speedup vs baseline: 1.0959x; 1.0959x over previous
//
#include <hip/hip_runtime.h>
#include <hip/hip_bf16.h>

typedef __attribute__((ext_vector_type(4))) float f32x4;
typedef __attribute__((ext_vector_type(8))) short short8;

__device__ inline unsigned short f2bf(float f) {
    union { float f; unsigned int u; } v; v.f = f;
    unsigned int u = v.u;
    return (unsigned short)((u + 0x7fffu + ((u >> 16) & 1u)) >> 16);
}
__device__ inline float bf2f(unsigned short h) {
    union { unsigned int u; float f; } v; v.u = ((unsigned int)h) << 16; return v.f;
}
__device__ inline float bflo(unsigned int p) {
    union { unsigned int u; float f; } v; v.u = p << 16; return v.f;
}
__device__ inline float bfhi(unsigned int p) {
    union { unsigned int u; float f; } v; v.u = p & 0xffff0000u; return v.f;
}
__device__ inline unsigned int packbf(float a, float b) {
    return (unsigned int)f2bf(a) | ((unsigned int)f2bf(b) << 16);
}

#define EPT 4096   // edges per chunk for range-partitioned passes

// ---------------- fp32 -> bf16 cast ----------------

__global__ __launch_bounds__(256) void cast_k(const float* __restrict__ x, unsigned short* __restrict__ y, int n4) {
    int i = blockIdx.x * 256 + threadIdx.x;
    if (i >= n4) return;
    f32x4 v = ((const f32x4*)x)[i];
    uint2 o; o.x = packbf(v[0], v[1]); o.y = packbf(v[2], v[3]);
    ((uint2*)y)[i] = o;
}

// ---------------- degree / CSR build (XCD-range-partitioned) ----------------

__global__ __launch_bounds__(256) void deg_count8_k(const int* __restrict__ dst, int* __restrict__ deg,
                                                    int e, int n, int n8) {
    int r = blockIdx.x & 7;
    int chunk = blockIdx.x >> 3;
    int base = chunk * EPT;
    int lim = base + EPT; if (lim > e) lim = e;
    int lo = r * n8;
    int hi = lo + n8; if (hi > n) hi = n;
    for (int i = base + threadIdx.x; i < lim; i += 256) {
        int d = dst[i];
        if (d >= lo && d < hi) atomicAdd(&deg[d], 1);
    }
}

__global__ __launch_bounds__(256) void partial_k(const int* __restrict__ deg, int* __restrict__ part, int n) {
    __shared__ int sm[256];
    int t = threadIdx.x;
    int base = blockIdx.x * 1024 + t * 4;
    int s = 0;
#pragma unroll
    for (int j = 0; j < 4; ++j) { int idx = base + j; if (idx < n) s += deg[idx]; }
    sm[t] = s;
    __syncthreads();
    for (int off = 128; off > 0; off >>= 1) {
        if (t < off) sm[t] += sm[t + off];
        __syncthreads();
    }
    if (t == 0) part[blockIdx.x] = sm[0];
}

__global__ __launch_bounds__(256) void scanpart_k(int* __restrict__ part, int nb) {
    __shared__ int sm[256];
    int t = threadIdx.x;
    int v = (t < nb) ? part[t] : 0;
    sm[t] = v;
    __syncthreads();
    for (int off = 1; off < 256; off <<= 1) {
        int u = (t >= off) ? sm[t - off] : 0;
        __syncthreads();
        sm[t] += u;
        __syncthreads();
    }
    if (t < nb) part[t] = sm[t] - v;   // exclusive
}

__global__ __launch_bounds__(256) void rowptr_k(const int* __restrict__ deg, const int* __restrict__ part,
                                                int* __restrict__ rowptr, int* __restrict__ cursor,
                                                float* __restrict__ dinv, int n) {
    __shared__ int sm[256];
    int t = threadIdx.x;
    int base = blockIdx.x * 1024 + t * 4;
    int d[4]; int s = 0;
#pragma unroll
    for (int j = 0; j < 4; ++j) { int idx = base + j; d[j] = (idx < n) ? deg[idx] : 0; s += d[j]; }
    sm[t] = s;
    __syncthreads();
    for (int off = 1; off < 256; off <<= 1) {
        int u = (t >= off) ? sm[t - off] : 0;
        __syncthreads();
        sm[t] += u;
        __syncthreads();
    }
    int ex = part[blockIdx.x] + sm[t] - s;
#pragma unroll
    for (int j = 0; j < 4; ++j) {
        int idx = base + j;
        if (idx < n) {
            rowptr[idx] = ex; cursor[idx] = ex;
            dinv[idx] = rsqrtf(fmaxf((float)d[j], 1.0f));
        }
        ex += d[j];
    }
    if (blockIdx.x == gridDim.x - 1 && t == 255) rowptr[n] = part[blockIdx.x] + sm[255];
}

__global__ __launch_bounds__(256) void scatter8_k(const int* __restrict__ src, const int* __restrict__ dst,
                                                  int* __restrict__ cursor, int* __restrict__ csrc,
                                                  int e, int n, int n8) {
    int r = blockIdx.x & 7;
    int chunk = blockIdx.x >> 3;
    int base = chunk * EPT;
    int lim = base + EPT; if (lim > e) lim = e;
    int lo = r * n8;
    int hi = lo + n8; if (hi > n) hi = n;
    for (int i = base + threadIdx.x; i < lim; i += 256) {
        int d = dst[i];
        if (d >= lo && d < hi) {
            int p = atomicAdd(&cursor[d], 1);
            csrc[p] = src[i];
        }
    }
}

// ---------------- SpMM (normalized adjacency), bf16 rows, CSR by dst ----------------

template<bool AFF>
__global__ __launch_bounds__(256) void spmm_bf_k(const unsigned short* __restrict__ x, const int* __restrict__ rowptr,
                                                 const int* __restrict__ csrc, const float* __restrict__ dinv,
                                                 const float* __restrict__ gscale, const float* __restrict__ goff,
                                                 unsigned short* __restrict__ out, int n) {
    int lane = threadIdx.x & 63;
    int wave = threadIdx.x >> 6;
    int node = blockIdx.x * 4 + wave;
    if (node >= n) return;
    int g = lane >> 4;        // edge group 0..3
    int c = lane & 15;        // uint4 column index: bf16 cols c*8 .. c*8+7
    int beg = rowptr[node], end = rowptr[node + 1];
    float acc[8];
    float sw = 0.f;
#pragma unroll
    for (int j = 0; j < 8; ++j) acc[j] = 0.f;

    int i = beg + g;
    for (; i + 12 < end; i += 16) {
        int s0 = csrc[i], s1 = csrc[i + 4], s2 = csrc[i + 8], s3 = csrc[i + 12];
        float w0 = dinv[s0], w1 = dinv[s1], w2 = dinv[s2], w3 = dinv[s3];
        uint4 v0 = ((const uint4*)(x + (size_t)s0 * 128))[c];
        uint4 v1 = ((const uint4*)(x + (size_t)s1 * 128))[c];
        uint4 v2 = ((const uint4*)(x + (size_t)s2 * 128))[c];
        uint4 v3 = ((const uint4*)(x + (size_t)s3 * 128))[c];
        if (AFF) sw += w0 + w1 + w2 + w3;
        acc[0] += w0 * bflo(v0.x); acc[1] += w0 * bfhi(v0.x);
        acc[2] += w0 * bflo(v0.y); acc[3] += w0 * bfhi(v0.y);
        acc[4] += w0 * bflo(v0.z); acc[5] += w0 * bfhi(v0.z);
        acc[6] += w0 * bflo(v0.w); acc[7] += w0 * bfhi(v0.w);
        acc[0] += w1 * bflo(v1.x); acc[1] += w1 * bfhi(v1.x);
        acc[2] += w1 * bflo(v1.y); acc[3] += w1 * bfhi(v1.y);
        acc[4] += w1 * bflo(v1.z); acc[5] += w1 * bfhi(v1.z);
        acc[6] += w1 * bflo(v1.w); acc[7] += w1 * bfhi(v1.w);
        acc[0] += w2 * bflo(v2.x); acc[1] += w2 * bfhi(v2.x);
        acc[2] += w2 * bflo(v2.y); acc[3] += w2 * bfhi(v2.y);
        acc[4] += w2 * bflo(v2.z); acc[5] += w2 * bfhi(v2.z);
        acc[6] += w2 * bflo(v2.w); acc[7] += w2 * bfhi(v2.w);
        acc[0] += w3 * bflo(v3.x); acc[1] += w3 * bfhi(v3.x);
        acc[2] += w3 * bflo(v3.y); acc[3] += w3 * bfhi(v3.y);
        acc[4] += w3 * bflo(v3.z); acc[5] += w3 * bfhi(v3.z);
        acc[6] += w3 * bflo(v3.w); acc[7] += w3 * bfhi(v3.w);
    }
    for (; i < end; i += 4) {
        int s0 = csrc[i];
        float w0 = dinv[s0];
        uint4 v0 = ((const uint4*)(x + (size_t)s0 * 128))[c];
        if (AFF) sw += w0;
        acc[0] += w0 * bflo(v0.x); acc[1] += w0 * bfhi(v0.x);
        acc[2] += w0 * bflo(v0.y); acc[3] += w0 * bfhi(v0.y);
        acc[4] += w0 * bflo(v0.z); acc[5] += w0 * bfhi(v0.z);
        acc[6] += w0 * bflo(v0.w); acc[7] += w0 * bfhi(v0.w);
    }

#pragma unroll
    for (int j = 0; j < 8; ++j) {
        acc[j] += __shfl_xor(acc[j], 16, 64);
        acc[j] += __shfl_xor(acc[j], 32, 64);
    }
    if (AFF) {
        sw += __shfl_xor(sw, 16, 64);
        sw += __shfl_xor(sw, 32, 64);
    }

    float dd = dinv[node];
    if (g == 0) {
        if (AFF) {
            f32x4 sc0 = ((const f32x4*)(gscale + c * 8))[0];
            f32x4 sc1 = ((const f32x4*)(gscale + c * 8))[1];
            f32x4 of0 = ((const f32x4*)(goff + c * 8))[0];
            f32x4 of1 = ((const f32x4*)(goff + c * 8))[1];
#pragma unroll
            for (int j = 0; j < 4; ++j) {
                acc[j] = sc0[j] * acc[j] + of0[j] * sw;
                acc[4 + j] = sc1[j] * acc[4 + j] + of1[j] * sw;
            }
        }
        uint4 o;
        o.x = packbf(acc[0] * dd, acc[1] * dd);
        o.y = packbf(acc[2] * dd, acc[3] * dd);
        o.z = packbf(acc[4] * dd, acc[5] * dd);
        o.w = packbf(acc[6] * dd, acc[7] * dd);
        ((uint4*)(out + (size_t)node * 128))[c] = o;
    }
}

// ---------------- weight packs (all 5 in one launch) ----------------

__device__ inline void pack_one(const float* __restrict__ W, unsigned short* __restrict__ out,
                                int K, int N, int cheb, int id) {
    int total = (K / 32) * (N / 16) * 64;
    if (id >= total) return;
    int lane = id & 63;
    int t2 = id >> 6;
    int nf = N / 16;
    int f = t2 % nf;
    int ks = t2 / nf;
    int col = f * 16 + (lane & 15);
    int kbase = ks * 32 + ((lane >> 4) * 8);
    for (int j = 0; j < 8; ++j) {
        int kg = kbase + j;
        float v;
        if (cheb) {
            int t = kg >> 7, kk = kg & 127;
            float w0 = W[kk * 128 + col], wb = W[16384 + kk * 128 + col], wc = W[32768 + kk * 128 + col];
            v = (t == 0) ? (w0 - wc) : (t == 1) ? (-wb) : (2.0f * wc);
        } else {
            v = W[(size_t)kg * N + col];
        }
        out[(size_t)id * 8 + j] = f2bf(v);
    }
}

__global__ __launch_bounds__(256) void pack_all_k(const float* W1, unsigned short* wp1,
                                                  const float* W2, unsigned short* wp2,
                                                  const float* W3, unsigned short* wp3,
                                                  const float* mw1, unsigned short* wpm1,
                                                  const float* mw2, unsigned short* wpm2) {
    int b = blockIdx.x, t = threadIdx.x;
    if (b < 24)       pack_one(W1, wp1, 384, 128, 1, b * 256 + t);
    else if (b < 48)  pack_one(W2, wp2, 384, 128, 1, (b - 24) * 256 + t);
    else if (b < 72)  pack_one(W3, wp3, 384, 128, 1, (b - 48) * 256 + t);
    else if (b < 80)  pack_one(mw1, wpm1, 128, 128, 0, (b - 72) * 256 + t);
    else              pack_one(mw2, wpm2, 128, 64, 0, (b - 80) * 256 + t);
}

// ---------------- BN coefficients from fused stats ----------------

__global__ __launch_bounds__(128) void bn_coef_k(const float* __restrict__ gsum, const float* __restrict__ gsqs,
                                                 const float* __restrict__ gamma, const float* __restrict__ beta,
                                                 float* __restrict__ gscale, float* __restrict__ goff, float inv_n) {
    int c = threadIdx.x;
    float mu = gsum[c] * inv_n;
    float var = gsqs[c] * inv_n - mu * mu;
    float sc = rsqrtf(var + 1e-5f) * gamma[c];
    gscale[c] = sc;
    goff[c] = beta[c] - mu * sc;
}

// ---------------- MFMA GEMM with LDS-staged B ----------------
// C[n x 128] = [s0|s1|s2](bf16) @ Wpack(96KB) + bias.  K=384, NF=8.
// B is the reused operand (every wave reads all 96KB): stage it in LDS in two
// 48KB halves via global_load_lds (zero VGPR cost, no spill), k-loop reads
// B-frags with contiguous ds_read_b128 (~12cy). A (read-once) stays global JIT.
// STATS: per-column sum/sumsq of outputs. AFFA: affine on s0 A-frags in-register.

template<bool RELU, bool RES, bool STATS, bool AFFA>
__global__ __launch_bounds__(256) void gemm_k(const unsigned short* __restrict__ s0,
                                              const unsigned short* __restrict__ s1,
                                              const unsigned short* __restrict__ s2,
                                              const unsigned short* __restrict__ wp,
                                              const float* __restrict__ bias,
                                              const unsigned short* __restrict__ resid,
                                              const float* __restrict__ gscale,
                                              const float* __restrict__ goff,
                                              float* __restrict__ gsum, float* __restrict__ gsqs,
                                              unsigned short* __restrict__ outp, int n) {
    __shared__ char blds[49152];          // 48 KiB: one half of Wpack
    __shared__ float bs[128], bq[128];
    int t = threadIdx.x;
    int lane = t & 63;
    int wave = t >> 6;
    int row0 = blockIdx.x * 64;

    if (STATS && t < 128) { bs[t] = 0.f; bq[t] = 0.f; }

    int rowA = row0 + wave * 16 + (lane & 15);
    if (rowA >= n) rowA = n - 1;
    int kg = (lane >> 4) * 8;

    f32x4 acc[8];
#pragma unroll
    for (int f = 0; f < 8; ++f) acc[f] = (f32x4)(0.0f);

#pragma unroll
    for (int half = 0; half < 2; ++half) {
        // stage 48KB of Wpack: each wave copies 12KB via 12 x global_load_lds(16B/lane)
        const char* gsrc = (const char*)wp + half * 49152;
        int wbase = wave * 12288;
#pragma unroll
        for (int j = 0; j < 12; ++j) {
            int off = wbase + j * 1024;
            __builtin_amdgcn_global_load_lds((const unsigned int*)(gsrc + off + lane * 16),
                                             (unsigned int*)(blds + off), 16, 0, 0);
        }
        __syncthreads();   // drains vmcnt before barrier

#pragma unroll
        for (int ks6 = 0; ks6 < 6; ++ks6) {
            int ks = half * 6 + ks6;
            const unsigned short* sp = (ks < 4) ? s0 : ((ks < 8) ? s1 : s2);
            int kk = (ks & 3) * 32 + kg;
            short8 a = *(const short8*)(sp + (size_t)rowA * 128 + kk);
            if (AFFA && ks < 4) {
                union { unsigned short u[8]; short8 v; } af;
#pragma unroll
                for (int j = 0; j < 8; ++j) {
                    float xv = bf2f((unsigned short)a[j]);
                    af.u[j] = f2bf(xv * gscale[kk + j] + goff[kk + j]);
                }
                a = af.v;
            }
#pragma unroll
            for (int f = 0; f < 8; ++f) {
                short8 bb = *(const short8*)(blds + (ks6 * 8 + f) * 1024 + lane * 16);
                acc[f] = __builtin_amdgcn_mfma_f32_16x16x32_bf16(a, bb, acc[f], 0, 0, 0);
            }
        }
        if (half == 0) __syncthreads();   // all waves done reading half 0
    }

    // ---- epilogue
    int colb = lane & 15;
    int rowD = row0 + wave * 16 + ((lane >> 4) << 2);
#pragma unroll
    for (int f = 0; f < 8; ++f) {
        int c = f * 16 + colb;
        float bv = bias[c];
        float ls = 0.f, lq = 0.f;
#pragma unroll
        for (int r = 0; r < 4; ++r) {
            int row = rowD + r;
            if (row >= n) continue;
            float v = acc[f][r] + bv;
            if (RELU) v = fmaxf(v, 0.0f);
            if (RES) v += bf2f(resid[(size_t)row * 128 + c]);
            if (STATS) { ls += v; lq += v * v; }
            outp[(size_t)row * 128 + c] = f2bf(v);
        }
        if (STATS) { atomicAdd(&bs[c], ls); atomicAdd(&bq[c], lq); }
    }

    if (STATS) {
        __syncthreads();
        if (t < 128) {
            atomicAdd(&gsum[t], bs[t]);
            atomicAdd(&gsqs[t], bq[t]);
        }
    }
}

// ---------------- fused MLP: out = relu(x@mw1+mb1)@mw2 + mb2 ----------------
// Stage wpm1(32KB)+wpm2(16KB) in LDS once; t-tile overlays the wpm1 region
// after GEMM1 (total 48KB). B-frags via ds_read_b128; A global / LDS.

__global__ __launch_bounds__(256) void mlp_fused_k(const unsigned short* __restrict__ x,
                                                   const unsigned short* __restrict__ wpm1,
                                                   const float* __restrict__ mb1,
                                                   const unsigned short* __restrict__ wpm2,
                                                   const float* __restrict__ mb2,
                                                   float* __restrict__ out, int n) {
    __shared__ char alds[49152];   // [0,32K)=wpm1 (later t-tile in [0,16K)), [32K,48K)=wpm2
    int t = threadIdx.x;
    int lane = t & 63;
    int wave = t >> 6;
    int row0 = blockIdx.x * 64 + wave * 16;
    int rowA = row0 + (lane & 15);
    if (rowA >= n) rowA = n - 1;
    int kg = (lane >> 4) * 8;
    int colb = lane & 15;

    // stage both weight packs (48KB concat): wave copies 12KB
    {
        int wbase = wave * 12288;
#pragma unroll
        for (int j = 0; j < 12; ++j) {
            int off = wbase + j * 1024;
            const char* g = (off < 32768) ? ((const char*)wpm1 + off)
                                          : ((const char*)wpm2 + (off - 32768));
            __builtin_amdgcn_global_load_lds((const unsigned int*)(g + lane * 16),
                                             (unsigned int*)(alds + off), 16, 0, 0);
        }
    }
    __syncthreads();

    // GEMM1: t = relu(x@mw1 + mb1)
    f32x4 acc[8];
#pragma unroll
    for (int f = 0; f < 8; ++f) acc[f] = (f32x4)(0.0f);
#pragma unroll
    for (int ks = 0; ks < 4; ++ks) {
        short8 a = *(const short8*)(x + (size_t)rowA * 128 + ks * 32 + kg);
#pragma unroll
        for (int f = 0; f < 8; ++f) {
            short8 b = *(const short8*)(alds + (ks * 8 + f) * 1024 + lane * 16);
            acc[f] = __builtin_amdgcn_mfma_f32_16x16x32_bf16(a, b, acc[f], 0, 0, 0);
        }
    }
    __syncthreads();   // everyone done reading wpm1 region

    int lrowD = wave * 16 + ((lane >> 4) << 2);
#pragma unroll
    for (int f = 0; f < 8; ++f) {
        int c = f * 16 + colb;
        float bv = mb1[c];
#pragma unroll
        for (int r = 0; r < 4; ++r) {
            int lrow = lrowD + r;
            float v = fmaxf(acc[f][r] + bv, 0.0f);
            int byte = lrow * 256 + c * 2;
            byte ^= ((lrow & 7) << 4);
            *(unsigned short*)(alds + byte) = f2bf(v);
        }
    }
    __syncthreads();

    // GEMM2: out = t@mw2 + mb2 (N=64)
    f32x4 acc2[4];
#pragma unroll
    for (int f = 0; f < 4; ++f) acc2[f] = (f32x4)(0.0f);
    int lrowA = wave * 16 + (lane & 15);
#pragma unroll
    for (int ks = 0; ks < 4; ++ks) {
        int byte = lrowA * 256 + (ks * 32 + kg) * 2;
        byte ^= ((lrowA & 7) << 4);
        short8 a = *(const short8*)(alds + byte);
#pragma unroll
        for (int f = 0; f < 4; ++f) {
            short8 b = *(const short8*)(alds + 32768 + (ks * 4 + f) * 1024 + lane * 16);
            acc2[f] = __builtin_amdgcn_mfma_f32_16x16x32_bf16(a, b, acc2[f], 0, 0, 0);
        }
    }
    int rowD = row0 + ((lane >> 4) << 2);
#pragma unroll
    for (int f = 0; f < 4; ++f) {
        int c = f * 16 + colb;
        float bv = mb2[c];
#pragma unroll
        for (int r = 0; r < 4; ++r) {
            int row = rowD + r;
            if (row >= n) continue;
            out[(size_t)row * 64 + c] = acc2[f][r] + bv;
        }
    }
}

// ---------------- launch ----------------

extern "C" void kernel_launch(void* const* d_in, const int* in_sizes, int n_in,
                              void* d_out, int out_size, void* d_ws, size_t ws_size,
                              hipStream_t stream) {
    const float* feat  = (const float*)d_in[0];
    const int*   src   = (const int*)d_in[1];
    const int*   dst   = (const int*)d_in[2];
    const float* W1    = (const float*)d_in[3];
    const float* b1    = (const float*)d_in[4];
    const float* W2    = (const float*)d_in[5];
    const float* b2    = (const float*)d_in[6];
    const float* W3    = (const float*)d_in[7];
    const float* b3    = (const float*)d_in[8];
    const float* gamma = (const float*)d_in[9];
    const float* beta  = (const float*)d_in[10];
    const float* mw1   = (const float*)d_in[11];
    const float* mb1   = (const float*)d_in[12];
    const float* mw2   = (const float*)d_in[13];
    const float* mb2   = (const float*)d_in[14];
    float* outp = (float*)d_out;

    const int n = in_sizes[0] / 128;
    const int e = in_sizes[1];
    const int n8 = (n + 7) / 8;

    char* w = (char*)d_ws;
    auto alloc = [&](size_t bytes) -> void* {
        void* p = (void*)w;
        w += (bytes + 255) & ~(size_t)255;
        return p;
    };
    unsigned short* featb = (unsigned short*)alloc((size_t)n * 128 * 2);
    unsigned short* buf0  = (unsigned short*)alloc((size_t)n * 128 * 2);
    unsigned short* buf1  = (unsigned short*)alloc((size_t)n * 128 * 2);
    unsigned short* buf2  = (unsigned short*)alloc((size_t)n * 128 * 2);
    unsigned short* buf3  = (unsigned short*)alloc((size_t)n * 128 * 2);
    int*   deg    = (int*)alloc((size_t)n * 4);
    float* dinv   = (float*)alloc((size_t)n * 4);
    int*   rowptr = (int*)alloc((size_t)(n + 1) * 4);
    int*   cursor = (int*)alloc((size_t)n * 4);
    int*   csrc   = (int*)alloc((size_t)e * 4);
    int*   part   = (int*)alloc(256 * 4);
    unsigned short* wp1  = (unsigned short*)alloc(12 * 8 * 512 * 2);
    unsigned short* wp2  = (unsigned short*)alloc(12 * 8 * 512 * 2);
    unsigned short* wp3  = (unsigned short*)alloc(12 * 8 * 512 * 2);
    unsigned short* wpm1 = (unsigned short*)alloc(4 * 8 * 512 * 2);
    unsigned short* wpm2 = (unsigned short*)alloc(4 * 4 * 512 * 2);
    float* gsum   = (float*)alloc(128 * 4);   // adjacent: one 1KB memset covers
    float* gsqs   = (float*)alloc(128 * 4);
    float* gscale = (float*)alloc(128 * 4);
    float* goff   = (float*)alloc(128 * 4);

    const int gGemm = (n + 63) / 64;
    const int gSpmm = (n + 3) / 4;
    const int nb = (n + 1023) / 1024;
    const int gE8 = 8 * ((e + EPT - 1) / EPT);

    // prep
    cast_k<<<(n * 32 + 255) / 256, 256, 0, stream>>>(feat, featb, n * 32);
    hipMemsetAsync(deg, 0, (size_t)n * 4, stream);
    hipMemsetAsync(gsum, 0, 1024, stream);   // gsum+gsqs (256-aligned adjacent)
    deg_count8_k<<<gE8, 256, 0, stream>>>(dst, deg, e, n, n8);
    partial_k<<<nb, 256, 0, stream>>>(deg, part, n);
    scanpart_k<<<1, 256, 0, stream>>>(part, nb);
    rowptr_k<<<nb, 256, 0, stream>>>(deg, part, rowptr, cursor, dinv, n);
    scatter8_k<<<gE8, 256, 0, stream>>>(src, dst, cursor, csrc, e, n, n8);
    pack_all_k<<<84, 256, 0, stream>>>(W1, wp1, W2, wp2, W3, wp3, mw1, wpm1, mw2, wpm2);

    // Layer 1: cheb(features, W1) -> relu -> buf0 (pre-BN), fused BN stats
    spmm_bf_k<false><<<gSpmm, 256, 0, stream>>>(featb, rowptr, csrc, dinv, nullptr, nullptr, buf1, n);
    spmm_bf_k<false><<<gSpmm, 256, 0, stream>>>(buf1, rowptr, csrc, dinv, nullptr, nullptr, buf2, n);
    gemm_k<true, false, true, false><<<gGemm, 256, 0, stream>>>(
        featb, buf1, buf2, wp1, b1, nullptr, nullptr, nullptr, gsum, gsqs, buf0, n);
    bn_coef_k<<<1, 128, 0, stream>>>(gsum, gsqs, gamma, beta, gscale, goff, 1.0f / (float)n);

    // Layer 2a: cheb(BN(buf0), W2) -> relu -> buf3  (BN fused into consumers)
    spmm_bf_k<true><<<gSpmm, 256, 0, stream>>>(buf0, rowptr, csrc, dinv, gscale, goff, buf1, n);
    spmm_bf_k<false><<<gSpmm, 256, 0, stream>>>(buf1, rowptr, csrc, dinv, nullptr, nullptr, buf2, n);
    gemm_k<true, false, false, true><<<gGemm, 256, 0, stream>>>(
        buf0, buf1, buf2, wp2, b2, nullptr, gscale, goff, nullptr, nullptr, buf3, n);

    // Layer 2b: cheb(buf3, W2) -> relu -> buf0
    spmm_bf_k<false><<<gSpmm, 256, 0, stream>>>(buf3, rowptr, csrc, dinv, nullptr, nullptr, buf1, n);
    spmm_bf_k<false><<<gSpmm, 256, 0, stream>>>(buf1, rowptr, csrc, dinv, nullptr, nullptr, buf2, n);
    gemm_k<true, false, false, false><<<gGemm, 256, 0, stream>>>(
        buf3, buf1, buf2, wp2, b2, nullptr, nullptr, nullptr, nullptr, nullptr, buf0, n);

    // Layer 3: cheb(buf0, W3) -> relu -> + residual(buf0) -> buf3
    spmm_bf_k<false><<<gSpmm, 256, 0, stream>>>(buf0, rowptr, csrc, dinv, nullptr, nullptr, buf1, n);
    spmm_bf_k<false><<<gSpmm, 256, 0, stream>>>(buf1, rowptr, csrc, dinv, nullptr, nullptr, buf2, n);
    gemm_k<true, true, false, false><<<gGemm, 256, 0, stream>>>(
        buf0, buf1, buf2, wp3, b3, buf0, nullptr, nullptr, nullptr, nullptr, buf3, n);

    // fused MLP
    mlp_fused_k<<<gGemm, 256, 0, stream>>>(buf3, wpm1, mb1, wpm2, mb2, outp, n);
}

// Round 10
// 482.266 us; speedup vs baseline: 1.1173x; 1.0195x over previous
//
#include <hip/hip_runtime.h>
#include <hip/hip_bf16.h>

typedef __attribute__((ext_vector_type(4))) float f32x4;
typedef __attribute__((ext_vector_type(8))) short short8;

__device__ inline unsigned short f2bf(float f) {
    union { float f; unsigned int u; } v; v.f = f;
    unsigned int u = v.u;
    return (unsigned short)((u + 0x7fffu + ((u >> 16) & 1u)) >> 16);
}
__device__ inline float bf2f(unsigned short h) {
    union { unsigned int u; float f; } v; v.u = ((unsigned int)h) << 16; return v.f;
}
__device__ inline float bflo(unsigned int p) {
    union { unsigned int u; float f; } v; v.u = p << 16; return v.f;
}
__device__ inline float bfhi(unsigned int p) {
    union { unsigned int u; float f; } v; v.u = p & 0xffff0000u; return v.f;
}
__device__ inline unsigned int packbf(float a, float b) {
    return (unsigned int)f2bf(a) | ((unsigned int)f2bf(b) << 16);
}

#define EPT 4096   // edges per chunk for range-partitioned passes

// ---------------- fp32 -> bf16 cast ----------------

__global__ __launch_bounds__(256) void cast_k(const float* __restrict__ x, unsigned short* __restrict__ y, int n4) {
    int i = blockIdx.x * 256 + threadIdx.x;
    if (i >= n4) return;
    f32x4 v = ((const f32x4*)x)[i];
    uint2 o; o.x = packbf(v[0], v[1]); o.y = packbf(v[2], v[3]);
    ((uint2*)y)[i] = o;
}

// ---------------- degree / CSR build (XCD-range-partitioned) ----------------

__global__ __launch_bounds__(256) void deg_count8_k(const int* __restrict__ dst, int* __restrict__ deg,
                                                    int e, int n, int n8) {
    int r = blockIdx.x & 7;
    int chunk = blockIdx.x >> 3;
    int base = chunk * EPT;
    int lim = base + EPT; if (lim > e) lim = e;
    int lo = r * n8;
    int hi = lo + n8; if (hi > n) hi = n;
    for (int i = base + threadIdx.x; i < lim; i += 256) {
        int d = dst[i];
        if (d >= lo && d < hi) atomicAdd(&deg[d], 1);
    }
}

__global__ __launch_bounds__(256) void partial_k(const int* __restrict__ deg, int* __restrict__ part, int n) {
    __shared__ int sm[256];
    int t = threadIdx.x;
    int base = blockIdx.x * 1024 + t * 4;
    int s = 0;
#pragma unroll
    for (int j = 0; j < 4; ++j) { int idx = base + j; if (idx < n) s += deg[idx]; }
    sm[t] = s;
    __syncthreads();
    for (int off = 128; off > 0; off >>= 1) {
        if (t < off) sm[t] += sm[t + off];
        __syncthreads();
    }
    if (t == 0) part[blockIdx.x] = sm[0];
}

__global__ __launch_bounds__(256) void scanpart_k(int* __restrict__ part, int nb) {
    __shared__ int sm[256];
    int t = threadIdx.x;
    int v = (t < nb) ? part[t] : 0;
    sm[t] = v;
    __syncthreads();
    for (int off = 1; off < 256; off <<= 1) {
        int u = (t >= off) ? sm[t - off] : 0;
        __syncthreads();
        sm[t] += u;
        __syncthreads();
    }
    if (t < nb) part[t] = sm[t] - v;   // exclusive
}

__global__ __launch_bounds__(256) void rowptr_k(const int* __restrict__ deg, const int* __restrict__ part,
                                                int* __restrict__ rowptr, int* __restrict__ cursor,
                                                float* __restrict__ dinv, int n) {
    __shared__ int sm[256];
    int t = threadIdx.x;
    int base = blockIdx.x * 1024 + t * 4;
    int d[4]; int s = 0;
#pragma unroll
    for (int j = 0; j < 4; ++j) { int idx = base + j; d[j] = (idx < n) ? deg[idx] : 0; s += d[j]; }
    sm[t] = s;
    __syncthreads();
    for (int off = 1; off < 256; off <<= 1) {
        int u = (t >= off) ? sm[t - off] : 0;
        __syncthreads();
        sm[t] += u;
        __syncthreads();
    }
    int ex = part[blockIdx.x] + sm[t] - s;
#pragma unroll
    for (int j = 0; j < 4; ++j) {
        int idx = base + j;
        if (idx < n) {
            rowptr[idx] = ex; cursor[idx] = ex;
            dinv[idx] = rsqrtf(fmaxf((float)d[j], 1.0f));
        }
        ex += d[j];
    }
    if (blockIdx.x == gridDim.x - 1 && t == 255) rowptr[n] = part[blockIdx.x] + sm[255];
}

__global__ __launch_bounds__(256) void scatter8_k(const int* __restrict__ src, const int* __restrict__ dst,
                                                  int* __restrict__ cursor, int* __restrict__ csrc,
                                                  int e, int n, int n8) {
    int r = blockIdx.x & 7;
    int chunk = blockIdx.x >> 3;
    int base = chunk * EPT;
    int lim = base + EPT; if (lim > e) lim = e;
    int lo = r * n8;
    int hi = lo + n8; if (hi > n) hi = n;
    for (int i = base + threadIdx.x; i < lim; i += 256) {
        int d = dst[i];
        if (d >= lo && d < hi) {
            int p = atomicAdd(&cursor[d], 1);
            csrc[p] = src[i];
        }
    }
}

// ---------------- SpMM (normalized adjacency), bf16 rows, CSR by dst ----------------

template<bool AFF>
__global__ __launch_bounds__(256) void spmm_bf_k(const unsigned short* __restrict__ x, const int* __restrict__ rowptr,
                                                 const int* __restrict__ csrc, const float* __restrict__ dinv,
                                                 const float* __restrict__ gscale, const float* __restrict__ goff,
                                                 unsigned short* __restrict__ out, int n) {
    int lane = threadIdx.x & 63;
    int wave = threadIdx.x >> 6;
    int node = blockIdx.x * 4 + wave;
    if (node >= n) return;
    int g = lane >> 4;        // edge group 0..3
    int c = lane & 15;        // uint4 column index: bf16 cols c*8 .. c*8+7
    int beg = rowptr[node], end = rowptr[node + 1];
    float acc[8];
    float sw = 0.f;
#pragma unroll
    for (int j = 0; j < 8; ++j) acc[j] = 0.f;

    int i = beg + g;
    for (; i + 12 < end; i += 16) {
        int s0 = csrc[i], s1 = csrc[i + 4], s2 = csrc[i + 8], s3 = csrc[i + 12];
        float w0 = dinv[s0], w1 = dinv[s1], w2 = dinv[s2], w3 = dinv[s3];
        uint4 v0 = ((const uint4*)(x + (size_t)s0 * 128))[c];
        uint4 v1 = ((const uint4*)(x + (size_t)s1 * 128))[c];
        uint4 v2 = ((const uint4*)(x + (size_t)s2 * 128))[c];
        uint4 v3 = ((const uint4*)(x + (size_t)s3 * 128))[c];
        if (AFF) sw += w0 + w1 + w2 + w3;
        acc[0] += w0 * bflo(v0.x); acc[1] += w0 * bfhi(v0.x);
        acc[2] += w0 * bflo(v0.y); acc[3] += w0 * bfhi(v0.y);
        acc[4] += w0 * bflo(v0.z); acc[5] += w0 * bfhi(v0.z);
        acc[6] += w0 * bflo(v0.w); acc[7] += w0 * bfhi(v0.w);
        acc[0] += w1 * bflo(v1.x); acc[1] += w1 * bfhi(v1.x);
        acc[2] += w1 * bflo(v1.y); acc[3] += w1 * bfhi(v1.y);
        acc[4] += w1 * bflo(v1.z); acc[5] += w1 * bfhi(v1.z);
        acc[6] += w1 * bflo(v1.w); acc[7] += w1 * bfhi(v1.w);
        acc[0] += w2 * bflo(v2.x); acc[1] += w2 * bfhi(v2.x);
        acc[2] += w2 * bflo(v2.y); acc[3] += w2 * bfhi(v2.y);
        acc[4] += w2 * bflo(v2.z); acc[5] += w2 * bfhi(v2.z);
        acc[6] += w2 * bflo(v2.w); acc[7] += w2 * bfhi(v2.w);
        acc[0] += w3 * bflo(v3.x); acc[1] += w3 * bfhi(v3.x);
        acc[2] += w3 * bflo(v3.y); acc[3] += w3 * bfhi(v3.y);
        acc[4] += w3 * bflo(v3.z); acc[5] += w3 * bfhi(v3.z);
        acc[6] += w3 * bflo(v3.w); acc[7] += w3 * bfhi(v3.w);
    }
    for (; i < end; i += 4) {
        int s0 = csrc[i];
        float w0 = dinv[s0];
        uint4 v0 = ((const uint4*)(x + (size_t)s0 * 128))[c];
        if (AFF) sw += w0;
        acc[0] += w0 * bflo(v0.x); acc[1] += w0 * bfhi(v0.x);
        acc[2] += w0 * bflo(v0.y); acc[3] += w0 * bfhi(v0.y);
        acc[4] += w0 * bflo(v0.z); acc[5] += w0 * bfhi(v0.z);
        acc[6] += w0 * bflo(v0.w); acc[7] += w0 * bfhi(v0.w);
    }

#pragma unroll
    for (int j = 0; j < 8; ++j) {
        acc[j] += __shfl_xor(acc[j], 16, 64);
        acc[j] += __shfl_xor(acc[j], 32, 64);
    }
    if (AFF) {
        sw += __shfl_xor(sw, 16, 64);
        sw += __shfl_xor(sw, 32, 64);
    }

    float dd = dinv[node];
    if (g == 0) {
        if (AFF) {
            f32x4 sc0 = ((const f32x4*)(gscale + c * 8))[0];
            f32x4 sc1 = ((const f32x4*)(gscale + c * 8))[1];
            f32x4 of0 = ((const f32x4*)(goff + c * 8))[0];
            f32x4 of1 = ((const f32x4*)(goff + c * 8))[1];
#pragma unroll
            for (int j = 0; j < 4; ++j) {
                acc[j] = sc0[j] * acc[j] + of0[j] * sw;
                acc[4 + j] = sc1[j] * acc[4 + j] + of1[j] * sw;
            }
        }
        uint4 o;
        o.x = packbf(acc[0] * dd, acc[1] * dd);
        o.y = packbf(acc[2] * dd, acc[3] * dd);
        o.z = packbf(acc[4] * dd, acc[5] * dd);
        o.w = packbf(acc[6] * dd, acc[7] * dd);
        ((uint4*)(out + (size_t)node * 128))[c] = o;
    }
}

// ---------------- weight packs (all 5 in one launch) ----------------

__device__ inline void pack_one(const float* __restrict__ W, unsigned short* __restrict__ out,
                                int K, int N, int cheb, int id) {
    int total = (K / 32) * (N / 16) * 64;
    if (id >= total) return;
    int lane = id & 63;
    int t2 = id >> 6;
    int nf = N / 16;
    int f = t2 % nf;
    int ks = t2 / nf;
    int col = f * 16 + (lane & 15);
    int kbase = ks * 32 + ((lane >> 4) * 8);
    for (int j = 0; j < 8; ++j) {
        int kg = kbase + j;
        float v;
        if (cheb) {
            int t = kg >> 7, kk = kg & 127;
            float w0 = W[kk * 128 + col], wb = W[16384 + kk * 128 + col], wc = W[32768 + kk * 128 + col];
            v = (t == 0) ? (w0 - wc) : (t == 1) ? (-wb) : (2.0f * wc);
        } else {
            v = W[(size_t)kg * N + col];
        }
        out[(size_t)id * 8 + j] = f2bf(v);
    }
}

__global__ __launch_bounds__(256) void pack_all_k(const float* W1, unsigned short* wp1,
                                                  const float* W2, unsigned short* wp2,
                                                  const float* W3, unsigned short* wp3,
                                                  const float* mw1, unsigned short* wpm1,
                                                  const float* mw2, unsigned short* wpm2) {
    int b = blockIdx.x, t = threadIdx.x;
    if (b < 24)       pack_one(W1, wp1, 384, 128, 1, b * 256 + t);
    else if (b < 48)  pack_one(W2, wp2, 384, 128, 1, (b - 24) * 256 + t);
    else if (b < 72)  pack_one(W3, wp3, 384, 128, 1, (b - 48) * 256 + t);
    else if (b < 80)  pack_one(mw1, wpm1, 128, 128, 0, (b - 72) * 256 + t);
    else              pack_one(mw2, wpm2, 128, 64, 0, (b - 80) * 256 + t);
}

// ---------------- BN coefficients from fused stats ----------------

__global__ __launch_bounds__(128) void bn_coef_k(const float* __restrict__ gsum, const float* __restrict__ gsqs,
                                                 const float* __restrict__ gamma, const float* __restrict__ beta,
                                                 float* __restrict__ gscale, float* __restrict__ goff, float inv_n) {
    int c = threadIdx.x;
    float mu = gsum[c] * inv_n;
    float var = gsqs[c] * inv_n - mu * mu;
    float sc = rsqrtf(var + 1e-5f) * gamma[c];
    gscale[c] = sc;
    goff[c] = beta[c] - mu * sc;
}

// ---------------- MFMA GEMM: LDS-staged B, register-preloaded A ----------------
// C[n x 128] = [s0|s1|s2](bf16) @ Wpack(96KB) + bias.  K=384, NF=8.
// __launch_bounds__(256,3): LDS caps at 3 blocks/CU anyway -> grant ~170 VGPR.
// All 12 A-frags preloaded (48 VGPR, independent, one combined latency wait with
// the first B-stage). B staged in two 48KB halves via global_load_lds (no VGPRs).

template<bool RELU, bool RES, bool STATS, bool AFFA>
__global__ __launch_bounds__(256, 3) void gemm_k(const unsigned short* __restrict__ s0,
                                                 const unsigned short* __restrict__ s1,
                                                 const unsigned short* __restrict__ s2,
                                                 const unsigned short* __restrict__ wp,
                                                 const float* __restrict__ bias,
                                                 const unsigned short* __restrict__ resid,
                                                 const float* __restrict__ gscale,
                                                 const float* __restrict__ goff,
                                                 float* __restrict__ gsum, float* __restrict__ gsqs,
                                                 unsigned short* __restrict__ outp, int n) {
    __shared__ char blds[49152];          // 48 KiB: one half of Wpack
    __shared__ float bs[128], bq[128];
    int t = threadIdx.x;
    int lane = t & 63;
    int wave = t >> 6;
    int row0 = blockIdx.x * 64;

    if (STATS && t < 128) { bs[t] = 0.f; bq[t] = 0.f; }

    int rowA = row0 + wave * 16 + (lane & 15);
    if (rowA >= n) rowA = n - 1;
    int kg = (lane >> 4) * 8;

    // ---- issue first B-half staging (48KB via global_load_lds, zero VGPRs)
    {
        const char* gsrc = (const char*)wp;
        int wbase = wave * 12288;
#pragma unroll
        for (int j = 0; j < 12; ++j) {
            int off = wbase + j * 1024;
            __builtin_amdgcn_global_load_lds((const unsigned int*)(gsrc + off + lane * 16),
                                             (unsigned int*)(blds + off), 16, 0, 0);
        }
    }

    // ---- preload ALL 12 A-frags (independent; in flight with the staging)
    short8 a[12];
#pragma unroll
    for (int ks = 0; ks < 12; ++ks) {
        const unsigned short* sp = (ks < 4) ? s0 : ((ks < 8) ? s1 : s2);
        int kk = (ks & 3) * 32 + kg;
        a[ks] = *(const short8*)(sp + (size_t)rowA * 128 + kk);
    }
    if (AFFA) {
#pragma unroll
        for (int ks = 0; ks < 4; ++ks) {
            int kk = ks * 32 + kg;
            union { unsigned short u[8]; short8 v; } af;
#pragma unroll
            for (int j = 0; j < 8; ++j) {
                float xv = bf2f((unsigned short)a[ks][j]);
                af.u[j] = f2bf(xv * gscale[kk + j] + goff[kk + j]);
            }
            a[ks] = af.v;
        }
    }

    f32x4 acc[8];
#pragma unroll
    for (int f = 0; f < 8; ++f) acc[f] = (f32x4)(0.0f);

#pragma unroll
    for (int half = 0; half < 2; ++half) {
        __syncthreads();   // drains vmcnt: staged B-half (and A on half 0) ready

#pragma unroll
        for (int ks6 = 0; ks6 < 6; ++ks6) {
            int ks = half * 6 + ks6;
#pragma unroll
            for (int f = 0; f < 8; ++f) {
                short8 bb = *(const short8*)(blds + (ks6 * 8 + f) * 1024 + lane * 16);
                acc[f] = __builtin_amdgcn_mfma_f32_16x16x32_bf16(a[ks], bb, acc[f], 0, 0, 0);
            }
        }

        if (half == 0) {
            __syncthreads();   // all waves done reading half 0
            const char* gsrc = (const char*)wp + 49152;
            int wbase = wave * 12288;
#pragma unroll
            for (int j = 0; j < 12; ++j) {
                int off = wbase + j * 1024;
                __builtin_amdgcn_global_load_lds((const unsigned int*)(gsrc + off + lane * 16),
                                                 (unsigned int*)(blds + off), 16, 0, 0);
            }
        }
    }

    // ---- epilogue
    int colb = lane & 15;
    int rowD = row0 + wave * 16 + ((lane >> 4) << 2);
#pragma unroll
    for (int f = 0; f < 8; ++f) {
        int c = f * 16 + colb;
        float bv = bias[c];
        float ls = 0.f, lq = 0.f;
#pragma unroll
        for (int r = 0; r < 4; ++r) {
            int row = rowD + r;
            if (row >= n) continue;
            float v = acc[f][r] + bv;
            if (RELU) v = fmaxf(v, 0.0f);
            if (RES) v += bf2f(resid[(size_t)row * 128 + c]);
            if (STATS) { ls += v; lq += v * v; }
            outp[(size_t)row * 128 + c] = f2bf(v);
        }
        if (STATS) { atomicAdd(&bs[c], ls); atomicAdd(&bq[c], lq); }
    }

    if (STATS) {
        __syncthreads();
        if (t < 128) {
            atomicAdd(&gsum[t], bs[t]);
            atomicAdd(&gsqs[t], bq[t]);
        }
    }
}

// ---------------- fused MLP: out = relu(x@mw1+mb1)@mw2 + mb2 ----------------
// Stage wpm1(32KB)+wpm2(16KB) in LDS once; t-tile overlays the wpm1 region
// after GEMM1 (total 48KB). A-frags preloaded to registers.

__global__ __launch_bounds__(256, 3) void mlp_fused_k(const unsigned short* __restrict__ x,
                                                      const unsigned short* __restrict__ wpm1,
                                                      const float* __restrict__ mb1,
                                                      const unsigned short* __restrict__ wpm2,
                                                      const float* __restrict__ mb2,
                                                      float* __restrict__ out, int n) {
    __shared__ char alds[49152];   // [0,32K)=wpm1 (later t-tile in [0,16K)), [32K,48K)=wpm2
    int t = threadIdx.x;
    int lane = t & 63;
    int wave = t >> 6;
    int row0 = blockIdx.x * 64 + wave * 16;
    int rowA = row0 + (lane & 15);
    if (rowA >= n) rowA = n - 1;
    int kg = (lane >> 4) * 8;
    int colb = lane & 15;

    // stage both weight packs (48KB concat): wave copies 12KB
    {
        int wbase = wave * 12288;
#pragma unroll
        for (int j = 0; j < 12; ++j) {
            int off = wbase + j * 1024;
            const char* g = (off < 32768) ? ((const char*)wpm1 + off)
                                          : ((const char*)wpm2 + (off - 32768));
            __builtin_amdgcn_global_load_lds((const unsigned int*)(g + lane * 16),
                                             (unsigned int*)(alds + off), 16, 0, 0);
        }
    }

    // preload the 4 A-frags (overlaps with staging)
    short8 a[4];
#pragma unroll
    for (int ks = 0; ks < 4; ++ks)
        a[ks] = *(const short8*)(x + (size_t)rowA * 128 + ks * 32 + kg);

    __syncthreads();

    // GEMM1: t = relu(x@mw1 + mb1)
    f32x4 acc[8];
#pragma unroll
    for (int f = 0; f < 8; ++f) acc[f] = (f32x4)(0.0f);
#pragma unroll
    for (int ks = 0; ks < 4; ++ks) {
#pragma unroll
        for (int f = 0; f < 8; ++f) {
            short8 b = *(const short8*)(alds + (ks * 8 + f) * 1024 + lane * 16);
            acc[f] = __builtin_amdgcn_mfma_f32_16x16x32_bf16(a[ks], b, acc[f], 0, 0, 0);
        }
    }
    __syncthreads();   // everyone done reading wpm1 region

    int lrowD = wave * 16 + ((lane >> 4) << 2);
#pragma unroll
    for (int f = 0; f < 8; ++f) {
        int c = f * 16 + colb;
        float bv = mb1[c];
#pragma unroll
        for (int r = 0; r < 4; ++r) {
            int lrow = lrowD + r;
            float v = fmaxf(acc[f][r] + bv, 0.0f);
            int byte = lrow * 256 + c * 2;
            byte ^= ((lrow & 7) << 4);
            *(unsigned short*)(alds + byte) = f2bf(v);
        }
    }
    __syncthreads();

    // GEMM2: out = t@mw2 + mb2 (N=64)
    f32x4 acc2[4];
#pragma unroll
    for (int f = 0; f < 4; ++f) acc2[f] = (f32x4)(0.0f);
    int lrowA = wave * 16 + (lane & 15);
#pragma unroll
    for (int ks = 0; ks < 4; ++ks) {
        int byte = lrowA * 256 + (ks * 32 + kg) * 2;
        byte ^= ((lrowA & 7) << 4);
        short8 av = *(const short8*)(alds + byte);
#pragma unroll
        for (int f = 0; f < 4; ++f) {
            short8 b = *(const short8*)(alds + 32768 + (ks * 4 + f) * 1024 + lane * 16);
            acc2[f] = __builtin_amdgcn_mfma_f32_16x16x32_bf16(av, b, acc2[f], 0, 0, 0);
        }
    }
    int rowD = row0 + ((lane >> 4) << 2);
#pragma unroll
    for (int f = 0; f < 4; ++f) {
        int c = f * 16 + colb;
        float bv = mb2[c];
#pragma unroll
        for (int r = 0; r < 4; ++r) {
            int row = rowD + r;
            if (row >= n) continue;
            out[(size_t)row * 64 + c] = acc2[f][r] + bv;
        }
    }
}

// ---------------- launch ----------------

extern "C" void kernel_launch(void* const* d_in, const int* in_sizes, int n_in,
                              void* d_out, int out_size, void* d_ws, size_t ws_size,
                              hipStream_t stream) {
    const float* feat  = (const float*)d_in[0];
    const int*   src   = (const int*)d_in[1];
    const int*   dst   = (const int*)d_in[2];
    const float* W1    = (const float*)d_in[3];
    const float* b1    = (const float*)d_in[4];
    const float* W2    = (const float*)d_in[5];
    const float* b2    = (const float*)d_in[6];
    const float* W3    = (const float*)d_in[7];
    const float* b3    = (const float*)d_in[8];
    const float* gamma = (const float*)d_in[9];
    const float* beta  = (const float*)d_in[10];
    const float* mw1   = (const float*)d_in[11];
    const float* mb1   = (const float*)d_in[12];
    const float* mw2   = (const float*)d_in[13];
    const float* mb2   = (const float*)d_in[14];
    float* outp = (float*)d_out;

    const int n = in_sizes[0] / 128;
    const int e = in_sizes[1];
    const int n8 = (n + 7) / 8;

    char* w = (char*)d_ws;
    auto alloc = [&](size_t bytes) -> void* {
        void* p = (void*)w;
        w += (bytes + 255) & ~(size_t)255;
        return p;
    };
    unsigned short* featb = (unsigned short*)alloc((size_t)n * 128 * 2);
    unsigned short* buf0  = (unsigned short*)alloc((size_t)n * 128 * 2);
    unsigned short* buf1  = (unsigned short*)alloc((size_t)n * 128 * 2);
    unsigned short* buf2  = (unsigned short*)alloc((size_t)n * 128 * 2);
    unsigned short* buf3  = (unsigned short*)alloc((size_t)n * 128 * 2);
    int*   deg    = (int*)alloc((size_t)n * 4);
    float* dinv   = (float*)alloc((size_t)n * 4);
    int*   rowptr = (int*)alloc((size_t)(n + 1) * 4);
    int*   cursor = (int*)alloc((size_t)n * 4);
    int*   csrc   = (int*)alloc((size_t)e * 4);
    int*   part   = (int*)alloc(256 * 4);
    unsigned short* wp1  = (unsigned short*)alloc(12 * 8 * 512 * 2);
    unsigned short* wp2  = (unsigned short*)alloc(12 * 8 * 512 * 2);
    unsigned short* wp3  = (unsigned short*)alloc(12 * 8 * 512 * 2);
    unsigned short* wpm1 = (unsigned short*)alloc(4 * 8 * 512 * 2);
    unsigned short* wpm2 = (unsigned short*)alloc(4 * 4 * 512 * 2);
    float* gsum   = (float*)alloc(128 * 4);   // adjacent: one 1KB memset covers
    float* gsqs   = (float*)alloc(128 * 4);
    float* gscale = (float*)alloc(128 * 4);
    float* goff   = (float*)alloc(128 * 4);

    const int gGemm = (n + 63) / 64;
    const int gSpmm = (n + 3) / 4;
    const int nb = (n + 1023) / 1024;
    const int gE8 = 8 * ((e + EPT - 1) / EPT);

    // prep
    cast_k<<<(n * 32 + 255) / 256, 256, 0, stream>>>(feat, featb, n * 32);
    hipMemsetAsync(deg, 0, (size_t)n * 4, stream);
    hipMemsetAsync(gsum, 0, 1024, stream);   // gsum+gsqs (256-aligned adjacent)
    deg_count8_k<<<gE8, 256, 0, stream>>>(dst, deg, e, n, n8);
    partial_k<<<nb, 256, 0, stream>>>(deg, part, n);
    scanpart_k<<<1, 256, 0, stream>>>(part, nb);
    rowptr_k<<<nb, 256, 0, stream>>>(deg, part, rowptr, cursor, dinv, n);
    scatter8_k<<<gE8, 256, 0, stream>>>(src, dst, cursor, csrc, e, n, n8);
    pack_all_k<<<84, 256, 0, stream>>>(W1, wp1, W2, wp2, W3, wp3, mw1, wpm1, mw2, wpm2);

    // Layer 1: cheb(features, W1) -> relu -> buf0 (pre-BN), fused BN stats
    spmm_bf_k<false><<<gSpmm, 256, 0, stream>>>(featb, rowptr, csrc, dinv, nullptr, nullptr, buf1, n);
    spmm_bf_k<false><<<gSpmm, 256, 0, stream>>>(buf1, rowptr, csrc, dinv, nullptr, nullptr, buf2, n);
    gemm_k<true, false, true, false><<<gGemm, 256, 0, stream>>>(
        featb, buf1, buf2, wp1, b1, nullptr, nullptr, nullptr, gsum, gsqs, buf0, n);
    bn_coef_k<<<1, 128, 0, stream>>>(gsum, gsqs, gamma, beta, gscale, goff, 1.0f / (float)n);

    // Layer 2a: cheb(BN(buf0), W2) -> relu -> buf3  (BN fused into consumers)
    spmm_bf_k<true><<<gSpmm, 256, 0, stream>>>(buf0, rowptr, csrc, dinv, gscale, goff, buf1, n);
    spmm_bf_k<false><<<gSpmm, 256, 0, stream>>>(buf1, rowptr, csrc, dinv, nullptr, nullptr, buf2, n);
    gemm_k<true, false, false, true><<<gGemm, 256, 0, stream>>>(
        buf0, buf1, buf2, wp2, b2, nullptr, gscale, goff, nullptr, nullptr, buf3, n);

    // Layer 2b: cheb(buf3, W2) -> relu -> buf0
    spmm_bf_k<false><<<gSpmm, 256, 0, stream>>>(buf3, rowptr, csrc, dinv, nullptr, nullptr, buf1, n);
    spmm_bf_k<false><<<gSpmm, 256, 0, stream>>>(buf1, rowptr, csrc, dinv, nullptr, nullptr, buf2, n);
    gemm_k<true, false, false, false><<<gGemm, 256, 0, stream>>>(
        buf3, buf1, buf2, wp2, b2, nullptr, nullptr, nullptr, nullptr, nullptr, buf0, n);

    // Layer 3: cheb(buf0, W3) -> relu -> + residual(buf0) -> buf3
    spmm_bf_k<false><<<gSpmm, 256, 0, stream>>>(buf0, rowptr, csrc, dinv, nullptr, nullptr, buf1, n);
    spmm_bf_k<false><<<gSpmm, 256, 0, stream>>>(buf1, rowptr, csrc, dinv, nullptr, nullptr, buf2, n);
    gemm_k<true, true, false, false><<<gGemm, 256, 0, stream>>>(
        buf0, buf1, buf2, wp3, b3, buf0, nullptr, nullptr, nullptr, nullptr, buf3, n);

    // fused MLP
    mlp_fused_k<<<gGemm, 256, 0, stream>>>(buf3, wpm1, mb1, wpm2, mb2, outp, n);
}

// Round 11
// 455.718 us; speedup vs baseline: 1.1824x; 1.0583x over previous
//
#include <hip/hip_runtime.h>
#include <hip/hip_bf16.h>

typedef __attribute__((ext_vector_type(4))) float f32x4;
typedef __attribute__((ext_vector_type(8))) short short8;

__device__ inline unsigned short f2bf(float f) {
    union { float f; unsigned int u; } v; v.f = f;
    unsigned int u = v.u;
    return (unsigned short)((u + 0x7fffu + ((u >> 16) & 1u)) >> 16);
}
__device__ inline float bf2f(unsigned short h) {
    union { unsigned int u; float f; } v; v.u = ((unsigned int)h) << 16; return v.f;
}
__device__ inline float bflo(unsigned int p) {
    union { unsigned int u; float f; } v; v.u = p << 16; return v.f;
}
__device__ inline float bfhi(unsigned int p) {
    union { unsigned int u; float f; } v; v.u = p & 0xffff0000u; return v.f;
}
__device__ inline unsigned int packbf(float a, float b) {
    return (unsigned int)f2bf(a) | ((unsigned int)f2bf(b) << 16);
}

#define EPT 4096   // edges per chunk for range-partitioned passes

// ---------------- fp32 -> bf16 cast ----------------

__global__ __launch_bounds__(256) void cast_k(const float* __restrict__ x, unsigned short* __restrict__ y, int n4) {
    int i = blockIdx.x * 256 + threadIdx.x;
    if (i >= n4) return;
    f32x4 v = ((const f32x4*)x)[i];
    uint2 o; o.x = packbf(v[0], v[1]); o.y = packbf(v[2], v[3]);
    ((uint2*)y)[i] = o;
}

// ---------------- degree / CSR build (XCD-range-partitioned) ----------------

__global__ __launch_bounds__(256) void deg_count8_k(const int* __restrict__ dst, int* __restrict__ deg,
                                                    int e, int n, int n8) {
    int r = blockIdx.x & 7;
    int chunk = blockIdx.x >> 3;
    int base = chunk * EPT;
    int lim = base + EPT; if (lim > e) lim = e;
    int lo = r * n8;
    int hi = lo + n8; if (hi > n) hi = n;
    for (int i = base + threadIdx.x; i < lim; i += 256) {
        int d = dst[i];
        if (d >= lo && d < hi) atomicAdd(&deg[d], 1);
    }
}

__global__ __launch_bounds__(256) void partial_k(const int* __restrict__ deg, int* __restrict__ part, int n) {
    __shared__ int sm[256];
    int t = threadIdx.x;
    int base = blockIdx.x * 1024 + t * 4;
    int s = 0;
#pragma unroll
    for (int j = 0; j < 4; ++j) { int idx = base + j; if (idx < n) s += deg[idx]; }
    sm[t] = s;
    __syncthreads();
    for (int off = 128; off > 0; off >>= 1) {
        if (t < off) sm[t] += sm[t + off];
        __syncthreads();
    }
    if (t == 0) part[blockIdx.x] = sm[0];
}

__global__ __launch_bounds__(256) void scanpart_k(int* __restrict__ part, int nb) {
    __shared__ int sm[256];
    int t = threadIdx.x;
    int v = (t < nb) ? part[t] : 0;
    sm[t] = v;
    __syncthreads();
    for (int off = 1; off < 256; off <<= 1) {
        int u = (t >= off) ? sm[t - off] : 0;
        __syncthreads();
        sm[t] += u;
        __syncthreads();
    }
    if (t < nb) part[t] = sm[t] - v;   // exclusive
}

__global__ __launch_bounds__(256) void rowptr_k(const int* __restrict__ deg, const int* __restrict__ part,
                                                int* __restrict__ rowptr, int* __restrict__ cursor,
                                                float* __restrict__ dinv, int n) {
    __shared__ int sm[256];
    int t = threadIdx.x;
    int base = blockIdx.x * 1024 + t * 4;
    int d[4]; int s = 0;
#pragma unroll
    for (int j = 0; j < 4; ++j) { int idx = base + j; d[j] = (idx < n) ? deg[idx] : 0; s += d[j]; }
    sm[t] = s;
    __syncthreads();
    for (int off = 1; off < 256; off <<= 1) {
        int u = (t >= off) ? sm[t - off] : 0;
        __syncthreads();
        sm[t] += u;
        __syncthreads();
    }
    int ex = part[blockIdx.x] + sm[t] - s;
#pragma unroll
    for (int j = 0; j < 4; ++j) {
        int idx = base + j;
        if (idx < n) {
            rowptr[idx] = ex; cursor[idx] = ex;
            dinv[idx] = rsqrtf(fmaxf((float)d[j], 1.0f));
        }
        ex += d[j];
    }
    if (blockIdx.x == gridDim.x - 1 && t == 255) rowptr[n] = part[blockIdx.x] + sm[255];
}

__global__ __launch_bounds__(256) void scatter8_k(const int* __restrict__ src, const int* __restrict__ dst,
                                                  int* __restrict__ cursor, int* __restrict__ csrc,
                                                  int e, int n, int n8) {
    int r = blockIdx.x & 7;
    int chunk = blockIdx.x >> 3;
    int base = chunk * EPT;
    int lim = base + EPT; if (lim > e) lim = e;
    int lo = r * n8;
    int hi = lo + n8; if (hi > n) hi = n;
    for (int i = base + threadIdx.x; i < lim; i += 256) {
        int d = dst[i];
        if (d >= lo && d < hi) {
            int p = atomicAdd(&cursor[d], 1);
            csrc[p] = src[i];
        }
    }
}

// ---------------- SpMM (normalized adjacency), bf16 rows, CSR by dst ----------------

template<bool AFF>
__global__ __launch_bounds__(256) void spmm_bf_k(const unsigned short* __restrict__ x, const int* __restrict__ rowptr,
                                                 const int* __restrict__ csrc, const float* __restrict__ dinv,
                                                 const float* __restrict__ gscale, const float* __restrict__ goff,
                                                 unsigned short* __restrict__ out, int n) {
    int lane = threadIdx.x & 63;
    int wave = threadIdx.x >> 6;
    int node = blockIdx.x * 4 + wave;
    if (node >= n) return;
    int g = lane >> 4;        // edge group 0..3
    int c = lane & 15;        // uint4 column index: bf16 cols c*8 .. c*8+7
    int beg = rowptr[node], end = rowptr[node + 1];
    float acc[8];
    float sw = 0.f;
#pragma unroll
    for (int j = 0; j < 8; ++j) acc[j] = 0.f;

    int i = beg + g;
    for (; i + 12 < end; i += 16) {
        int s0 = csrc[i], s1 = csrc[i + 4], s2 = csrc[i + 8], s3 = csrc[i + 12];
        float w0 = dinv[s0], w1 = dinv[s1], w2 = dinv[s2], w3 = dinv[s3];
        uint4 v0 = ((const uint4*)(x + (size_t)s0 * 128))[c];
        uint4 v1 = ((const uint4*)(x + (size_t)s1 * 128))[c];
        uint4 v2 = ((const uint4*)(x + (size_t)s2 * 128))[c];
        uint4 v3 = ((const uint4*)(x + (size_t)s3 * 128))[c];
        if (AFF) sw += w0 + w1 + w2 + w3;
        acc[0] += w0 * bflo(v0.x); acc[1] += w0 * bfhi(v0.x);
        acc[2] += w0 * bflo(v0.y); acc[3] += w0 * bfhi(v0.y);
        acc[4] += w0 * bflo(v0.z); acc[5] += w0 * bfhi(v0.z);
        acc[6] += w0 * bflo(v0.w); acc[7] += w0 * bfhi(v0.w);
        acc[0] += w1 * bflo(v1.x); acc[1] += w1 * bfhi(v1.x);
        acc[2] += w1 * bflo(v1.y); acc[3] += w1 * bfhi(v1.y);
        acc[4] += w1 * bflo(v1.z); acc[5] += w1 * bfhi(v1.z);
        acc[6] += w1 * bflo(v1.w); acc[7] += w1 * bfhi(v1.w);
        acc[0] += w2 * bflo(v2.x); acc[1] += w2 * bfhi(v2.x);
        acc[2] += w2 * bflo(v2.y); acc[3] += w2 * bfhi(v2.y);
        acc[4] += w2 * bflo(v2.z); acc[5] += w2 * bfhi(v2.z);
        acc[6] += w2 * bflo(v2.w); acc[7] += w2 * bfhi(v2.w);
        acc[0] += w3 * bflo(v3.x); acc[1] += w3 * bfhi(v3.x);
        acc[2] += w3 * bflo(v3.y); acc[3] += w3 * bfhi(v3.y);
        acc[4] += w3 * bflo(v3.z); acc[5] += w3 * bfhi(v3.z);
        acc[6] += w3 * bflo(v3.w); acc[7] += w3 * bfhi(v3.w);
    }
    for (; i < end; i += 4) {
        int s0 = csrc[i];
        float w0 = dinv[s0];
        uint4 v0 = ((const uint4*)(x + (size_t)s0 * 128))[c];
        if (AFF) sw += w0;
        acc[0] += w0 * bflo(v0.x); acc[1] += w0 * bfhi(v0.x);
        acc[2] += w0 * bflo(v0.y); acc[3] += w0 * bfhi(v0.y);
        acc[4] += w0 * bflo(v0.z); acc[5] += w0 * bfhi(v0.z);
        acc[6] += w0 * bflo(v0.w); acc[7] += w0 * bfhi(v0.w);
    }

#pragma unroll
    for (int j = 0; j < 8; ++j) {
        acc[j] += __shfl_xor(acc[j], 16, 64);
        acc[j] += __shfl_xor(acc[j], 32, 64);
    }
    if (AFF) {
        sw += __shfl_xor(sw, 16, 64);
        sw += __shfl_xor(sw, 32, 64);
    }

    float dd = dinv[node];
    if (g == 0) {
        if (AFF) {
            f32x4 sc0 = ((const f32x4*)(gscale + c * 8))[0];
            f32x4 sc1 = ((const f32x4*)(gscale + c * 8))[1];
            f32x4 of0 = ((const f32x4*)(goff + c * 8))[0];
            f32x4 of1 = ((const f32x4*)(goff + c * 8))[1];
#pragma unroll
            for (int j = 0; j < 4; ++j) {
                acc[j] = sc0[j] * acc[j] + of0[j] * sw;
                acc[4 + j] = sc1[j] * acc[4 + j] + of1[j] * sw;
            }
        }
        uint4 o;
        o.x = packbf(acc[0] * dd, acc[1] * dd);
        o.y = packbf(acc[2] * dd, acc[3] * dd);
        o.z = packbf(acc[4] * dd, acc[5] * dd);
        o.w = packbf(acc[6] * dd, acc[7] * dd);
        ((uint4*)(out + (size_t)node * 128))[c] = o;
    }
}

// ---------------- weight packs (all 5 in one launch) ----------------

__device__ inline void pack_one(const float* __restrict__ W, unsigned short* __restrict__ out,
                                int K, int N, int cheb, int id) {
    int total = (K / 32) * (N / 16) * 64;
    if (id >= total) return;
    int lane = id & 63;
    int t2 = id >> 6;
    int nf = N / 16;
    int f = t2 % nf;
    int ks = t2 / nf;
    int col = f * 16 + (lane & 15);
    int kbase = ks * 32 + ((lane >> 4) * 8);
    for (int j = 0; j < 8; ++j) {
        int kg = kbase + j;
        float v;
        if (cheb) {
            int t = kg >> 7, kk = kg & 127;
            float w0 = W[kk * 128 + col], wb = W[16384 + kk * 128 + col], wc = W[32768 + kk * 128 + col];
            v = (t == 0) ? (w0 - wc) : (t == 1) ? (-wb) : (2.0f * wc);
        } else {
            v = W[(size_t)kg * N + col];
        }
        out[(size_t)id * 8 + j] = f2bf(v);
    }
}

__global__ __launch_bounds__(256) void pack_all_k(const float* W1, unsigned short* wp1,
                                                  const float* W2, unsigned short* wp2,
                                                  const float* W3, unsigned short* wp3,
                                                  const float* mw1, unsigned short* wpm1,
                                                  const float* mw2, unsigned short* wpm2) {
    int b = blockIdx.x, t = threadIdx.x;
    if (b < 24)       pack_one(W1, wp1, 384, 128, 1, b * 256 + t);
    else if (b < 48)  pack_one(W2, wp2, 384, 128, 1, (b - 24) * 256 + t);
    else if (b < 72)  pack_one(W3, wp3, 384, 128, 1, (b - 48) * 256 + t);
    else if (b < 80)  pack_one(mw1, wpm1, 128, 128, 0, (b - 72) * 256 + t);
    else              pack_one(mw2, wpm2, 128, 64, 0, (b - 80) * 256 + t);
}

// ---------------- BN coefficients from fused stats ----------------

__global__ __launch_bounds__(128) void bn_coef_k(const float* __restrict__ gsum, const float* __restrict__ gsqs,
                                                 const float* __restrict__ gamma, const float* __restrict__ beta,
                                                 float* __restrict__ gscale, float* __restrict__ goff, float inv_n) {
    int c = threadIdx.x;
    float mu = gsum[c] * inv_n;
    float var = gsqs[c] * inv_n - mu * mu;
    float sc = rsqrtf(var + 1e-5f) * gamma[c];
    gscale[c] = sc;
    goff[c] = beta[c] - mu * sc;
}

// ---------------- MFMA GEMM: 512 threads / 128 rows, LDS-staged B ----------------
// C[n x 128] = [s0|s1|s2](bf16) @ Wpack(96KB) + bias.  K=384.
// 8 waves x 16 rows. B staged in two 48KB halves via global_load_lds (6KB/wave).
// A: 12 frags preloaded + asm keep-alive (prevents the compiler sinking the loads).
// STATS: per-column sum/sumsq. AFFA: affine on s0 frags. MLP: fuse the 2-layer
// MLP tail (y never leaves the CU: y->LDS t-tile, restage wpm1/wpm2 into blds,
// GEMM1 -> GEMM2 -> fp32 out).

template<bool RELU, bool RES, bool STATS, bool AFFA, bool MLP>
__global__ __launch_bounds__(512, 4) void gemm_k(const unsigned short* __restrict__ s0,
                                                 const unsigned short* __restrict__ s1,
                                                 const unsigned short* __restrict__ s2,
                                                 const unsigned short* __restrict__ wp,
                                                 const float* __restrict__ bias,
                                                 const unsigned short* __restrict__ resid,
                                                 const float* __restrict__ gscale,
                                                 const float* __restrict__ goff,
                                                 float* __restrict__ gsum, float* __restrict__ gsqs,
                                                 unsigned short* __restrict__ outp,
                                                 const unsigned short* __restrict__ wpm1,
                                                 const float* __restrict__ mb1,
                                                 const unsigned short* __restrict__ wpm2,
                                                 const float* __restrict__ mb2,
                                                 float* __restrict__ outf, int n) {
    __shared__ char blds[49152];                  // one 48KB half of Wpack / later wpm1+wpm2
    __shared__ char tl[MLP ? 32768 : 16];         // MLP: 128x128 bf16 t-tile
    __shared__ float bs[STATS ? 128 : 1], bq[STATS ? 128 : 1];
    int t = threadIdx.x;
    int lane = t & 63;
    int wave = t >> 6;                            // 0..7
    int row0 = blockIdx.x * 128;

    if (STATS && t < 128) { bs[t] = 0.f; bq[t] = 0.f; }

    int rowA = row0 + wave * 16 + (lane & 15);
    if (rowA >= n) rowA = n - 1;
    int kg = (lane >> 4) * 8;
    int colb = lane & 15;

    // ---- issue first B-half staging (48KB; 6KB per wave)
    {
        const char* gsrc = (const char*)wp;
        int wbase = wave * 6144;
#pragma unroll
        for (int j = 0; j < 6; ++j) {
            int off = wbase + j * 1024;
            __builtin_amdgcn_global_load_lds((const unsigned int*)(gsrc + off + lane * 16),
                                             (unsigned int*)(blds + off), 16, 0, 0);
        }
    }

    // ---- preload ALL 12 A-frags; keep-alive pins the loads here
    short8 a[12];
#pragma unroll
    for (int ks = 0; ks < 12; ++ks) {
        const unsigned short* sp = (ks < 4) ? s0 : ((ks < 8) ? s1 : s2);
        int kk = (ks & 3) * 32 + kg;
        a[ks] = *(const short8*)(sp + (size_t)rowA * 128 + kk);
    }
    if (AFFA) {
#pragma unroll
        for (int ks = 0; ks < 4; ++ks) {
            int kk = ks * 32 + kg;
            union { unsigned short u[8]; short8 v; } af;
#pragma unroll
            for (int j = 0; j < 8; ++j) {
                float xv = bf2f((unsigned short)a[ks][j]);
                af.u[j] = f2bf(xv * gscale[kk + j] + goff[kk + j]);
            }
            a[ks] = af.v;
        }
    }
#pragma unroll
    for (int ks = 0; ks < 12; ++ks) {
        f32x4 kv = *(f32x4*)&a[ks];
        asm volatile("" :: "v"(kv));   // force materialization before the barrier
    }

    f32x4 acc[8];
#pragma unroll
    for (int f = 0; f < 8; ++f) acc[f] = (f32x4)(0.0f);

#pragma unroll
    for (int half = 0; half < 2; ++half) {
        __syncthreads();   // drains vmcnt: staged B-half ready

#pragma unroll
        for (int ks6 = 0; ks6 < 6; ++ks6) {
            int ks = half * 6 + ks6;
#pragma unroll
            for (int f = 0; f < 8; ++f) {
                short8 bb = *(const short8*)(blds + (ks6 * 8 + f) * 1024 + lane * 16);
                acc[f] = __builtin_amdgcn_mfma_f32_16x16x32_bf16(a[ks], bb, acc[f], 0, 0, 0);
            }
        }

        if (half == 0) {
            __syncthreads();   // all waves done reading half 0
            const char* gsrc = (const char*)wp + 49152;
            int wbase = wave * 6144;
#pragma unroll
            for (int j = 0; j < 6; ++j) {
                int off = wbase + j * 1024;
                __builtin_amdgcn_global_load_lds((const unsigned int*)(gsrc + off + lane * 16),
                                                 (unsigned int*)(blds + off), 16, 0, 0);
            }
        }
    }

    // ---- epilogue: v = relu(acc+bias) [+ resid]
    int rowD = row0 + wave * 16 + ((lane >> 4) << 2);
    int lrowD = wave * 16 + ((lane >> 4) << 2);
#pragma unroll
    for (int f = 0; f < 8; ++f) {
        int c = f * 16 + colb;
        float bv = bias[c];
        float ls = 0.f, lq = 0.f;
#pragma unroll
        for (int r = 0; r < 4; ++r) {
            int row = rowD + r;
            if (row >= n) continue;
            float v = acc[f][r] + bv;
            if (RELU) v = fmaxf(v, 0.0f);
            if (RES) v += bf2f(resid[(size_t)row * 128 + c]);
            if (STATS) { ls += v; lq += v * v; }
            if (MLP) {
                int lrow = lrowD + r;
                int byte = lrow * 256 + c * 2;
                byte ^= ((lrow & 7) << 4);
                *(unsigned short*)(tl + byte) = f2bf(v);
            } else {
                outp[(size_t)row * 128 + c] = f2bf(v);
            }
        }
        if (STATS) { atomicAdd(&bs[c], ls); atomicAdd(&bq[c], lq); }
    }

    if (STATS) {
        __syncthreads();
        if (t < 128) {
            atomicAdd(&gsum[t], bs[t]);
            atomicAdd(&gsqs[t], bq[t]);
        }
    }

    if (MLP) {
        __syncthreads();   // t-tile complete; blds reads complete
        // restage blds with wpm1 (32KB) + wpm2 (16KB)
        {
            int wbase = wave * 6144;
#pragma unroll
            for (int j = 0; j < 6; ++j) {
                int off = wbase + j * 1024;
                const char* g = (off < 32768) ? ((const char*)wpm1 + off)
                                              : ((const char*)wpm2 + (off - 32768));
                __builtin_amdgcn_global_load_lds((const unsigned int*)(g + lane * 16),
                                                 (unsigned int*)(blds + off), 16, 0, 0);
            }
        }
        __syncthreads();   // drains vmcnt

        // GEMM1: t2 = relu(y@mw1 + mb1)
        int lrowA = wave * 16 + (lane & 15);
        f32x4 acc2[8];
#pragma unroll
        for (int f = 0; f < 8; ++f) acc2[f] = (f32x4)(0.0f);
#pragma unroll
        for (int ks = 0; ks < 4; ++ks) {
            int byte = lrowA * 256 + (ks * 32 + kg) * 2;
            byte ^= ((lrowA & 7) << 4);
            short8 av = *(const short8*)(tl + byte);
#pragma unroll
            for (int f = 0; f < 8; ++f) {
                short8 b = *(const short8*)(blds + (ks * 8 + f) * 1024 + lane * 16);
                acc2[f] = __builtin_amdgcn_mfma_f32_16x16x32_bf16(av, b, acc2[f], 0, 0, 0);
            }
        }
        __syncthreads();   // all t-tile reads done before overwrite

#pragma unroll
        for (int f = 0; f < 8; ++f) {
            int c = f * 16 + colb;
            float bv = mb1[c];
#pragma unroll
            for (int r = 0; r < 4; ++r) {
                int lrow = lrowD + r;
                float v = fmaxf(acc2[f][r] + bv, 0.0f);
                int byte = lrow * 256 + c * 2;
                byte ^= ((lrow & 7) << 4);
                *(unsigned short*)(tl + byte) = f2bf(v);
            }
        }
        __syncthreads();

        // GEMM2: out = t2@mw2 + mb2 (N=64, fp32)
        f32x4 acc3[4];
#pragma unroll
        for (int f = 0; f < 4; ++f) acc3[f] = (f32x4)(0.0f);
#pragma unroll
        for (int ks = 0; ks < 4; ++ks) {
            int byte = lrowA * 256 + (ks * 32 + kg) * 2;
            byte ^= ((lrowA & 7) << 4);
            short8 av = *(const short8*)(tl + byte);
#pragma unroll
            for (int f = 0; f < 4; ++f) {
                short8 b = *(const short8*)(blds + 32768 + (ks * 4 + f) * 1024 + lane * 16);
                acc3[f] = __builtin_amdgcn_mfma_f32_16x16x32_bf16(av, b, acc3[f], 0, 0, 0);
            }
        }
#pragma unroll
        for (int f = 0; f < 4; ++f) {
            int c = f * 16 + colb;
            float bv = mb2[c];
#pragma unroll
            for (int r = 0; r < 4; ++r) {
                int row = rowD + r;
                if (row >= n) continue;
                outf[(size_t)row * 64 + c] = acc3[f][r] + bv;
            }
        }
    }
}

// ---------------- launch ----------------

extern "C" void kernel_launch(void* const* d_in, const int* in_sizes, int n_in,
                              void* d_out, int out_size, void* d_ws, size_t ws_size,
                              hipStream_t stream) {
    const float* feat  = (const float*)d_in[0];
    const int*   src   = (const int*)d_in[1];
    const int*   dst   = (const int*)d_in[2];
    const float* W1    = (const float*)d_in[3];
    const float* b1    = (const float*)d_in[4];
    const float* W2    = (const float*)d_in[5];
    const float* b2    = (const float*)d_in[6];
    const float* W3    = (const float*)d_in[7];
    const float* b3    = (const float*)d_in[8];
    const float* gamma = (const float*)d_in[9];
    const float* beta  = (const float*)d_in[10];
    const float* mw1   = (const float*)d_in[11];
    const float* mb1   = (const float*)d_in[12];
    const float* mw2   = (const float*)d_in[13];
    const float* mb2   = (const float*)d_in[14];
    float* outp = (float*)d_out;

    const int n = in_sizes[0] / 128;
    const int e = in_sizes[1];
    const int n8 = (n + 7) / 8;

    char* w = (char*)d_ws;
    auto alloc = [&](size_t bytes) -> void* {
        void* p = (void*)w;
        w += (bytes + 255) & ~(size_t)255;
        return p;
    };
    unsigned short* featb = (unsigned short*)alloc((size_t)n * 128 * 2);
    unsigned short* buf0  = (unsigned short*)alloc((size_t)n * 128 * 2);
    unsigned short* buf1  = (unsigned short*)alloc((size_t)n * 128 * 2);
    unsigned short* buf2  = (unsigned short*)alloc((size_t)n * 128 * 2);
    unsigned short* buf3  = (unsigned short*)alloc((size_t)n * 128 * 2);
    int*   deg    = (int*)alloc((size_t)n * 4);
    float* dinv   = (float*)alloc((size_t)n * 4);
    int*   rowptr = (int*)alloc((size_t)(n + 1) * 4);
    int*   cursor = (int*)alloc((size_t)n * 4);
    int*   csrc   = (int*)alloc((size_t)e * 4);
    int*   part   = (int*)alloc(256 * 4);
    unsigned short* wp1  = (unsigned short*)alloc(12 * 8 * 512 * 2);
    unsigned short* wp2  = (unsigned short*)alloc(12 * 8 * 512 * 2);
    unsigned short* wp3  = (unsigned short*)alloc(12 * 8 * 512 * 2);
    unsigned short* wpm1 = (unsigned short*)alloc(4 * 8 * 512 * 2);
    unsigned short* wpm2 = (unsigned short*)alloc(4 * 4 * 512 * 2);
    float* gsum   = (float*)alloc(128 * 4);   // adjacent: one 1KB memset covers
    float* gsqs   = (float*)alloc(128 * 4);
    float* gscale = (float*)alloc(128 * 4);
    float* goff   = (float*)alloc(128 * 4);

    const int gGemm = (n + 127) / 128;
    const int gSpmm = (n + 3) / 4;
    const int nb = (n + 1023) / 1024;
    const int gE8 = 8 * ((e + EPT - 1) / EPT);

    // prep
    cast_k<<<(n * 32 + 255) / 256, 256, 0, stream>>>(feat, featb, n * 32);
    hipMemsetAsync(deg, 0, (size_t)n * 4, stream);
    hipMemsetAsync(gsum, 0, 1024, stream);   // gsum+gsqs (256-aligned adjacent)
    deg_count8_k<<<gE8, 256, 0, stream>>>(dst, deg, e, n, n8);
    partial_k<<<nb, 256, 0, stream>>>(deg, part, n);
    scanpart_k<<<1, 256, 0, stream>>>(part, nb);
    rowptr_k<<<nb, 256, 0, stream>>>(deg, part, rowptr, cursor, dinv, n);
    scatter8_k<<<gE8, 256, 0, stream>>>(src, dst, cursor, csrc, e, n, n8);
    pack_all_k<<<84, 256, 0, stream>>>(W1, wp1, W2, wp2, W3, wp3, mw1, wpm1, mw2, wpm2);

    // Layer 1: cheb(features, W1) -> relu -> buf0 (pre-BN), fused BN stats
    spmm_bf_k<false><<<gSpmm, 256, 0, stream>>>(featb, rowptr, csrc, dinv, nullptr, nullptr, buf1, n);
    spmm_bf_k<false><<<gSpmm, 256, 0, stream>>>(buf1, rowptr, csrc, dinv, nullptr, nullptr, buf2, n);
    gemm_k<true, false, true, false, false><<<gGemm, 512, 0, stream>>>(
        featb, buf1, buf2, wp1, b1, nullptr, nullptr, nullptr, gsum, gsqs, buf0,
        nullptr, nullptr, nullptr, nullptr, nullptr, n);
    bn_coef_k<<<1, 128, 0, stream>>>(gsum, gsqs, gamma, beta, gscale, goff, 1.0f / (float)n);

    // Layer 2a: cheb(BN(buf0), W2) -> relu -> buf3  (BN fused into consumers)
    spmm_bf_k<true><<<gSpmm, 256, 0, stream>>>(buf0, rowptr, csrc, dinv, gscale, goff, buf1, n);
    spmm_bf_k<false><<<gSpmm, 256, 0, stream>>>(buf1, rowptr, csrc, dinv, nullptr, nullptr, buf2, n);
    gemm_k<true, false, false, true, false><<<gGemm, 512, 0, stream>>>(
        buf0, buf1, buf2, wp2, b2, nullptr, gscale, goff, nullptr, nullptr, buf3,
        nullptr, nullptr, nullptr, nullptr, nullptr, n);

    // Layer 2b: cheb(buf3, W2) -> relu -> buf0
    spmm_bf_k<false><<<gSpmm, 256, 0, stream>>>(buf3, rowptr, csrc, dinv, nullptr, nullptr, buf1, n);
    spmm_bf_k<false><<<gSpmm, 256, 0, stream>>>(buf1, rowptr, csrc, dinv, nullptr, nullptr, buf2, n);
    gemm_k<true, false, false, false, false><<<gGemm, 512, 0, stream>>>(
        buf3, buf1, buf2, wp2, b2, nullptr, nullptr, nullptr, nullptr, nullptr, buf0,
        nullptr, nullptr, nullptr, nullptr, nullptr, n);

    // Layer 3 + MLP fused: out = relu(relu(cheb)+resid @ mw1+mb1)@mw2 + mb2
    spmm_bf_k<false><<<gSpmm, 256, 0, stream>>>(buf0, rowptr, csrc, dinv, nullptr, nullptr, buf1, n);
    spmm_bf_k<false><<<gSpmm, 256, 0, stream>>>(buf1, rowptr, csrc, dinv, nullptr, nullptr, buf2, n);
    gemm_k<true, true, false, false, true><<<gGemm, 512, 0, stream>>>(
        buf0, buf1, buf2, wp3, b3, buf0, nullptr, nullptr, nullptr, nullptr, nullptr,
        wpm1, mb1, wpm2, mb2, outp, n);
}

// Round 12
// 433.558 us; speedup vs baseline: 1.2428x; 1.0511x over previous
//
#include <hip/hip_runtime.h>
#include <hip/hip_bf16.h>

typedef __attribute__((ext_vector_type(4))) float f32x4;
typedef __attribute__((ext_vector_type(8))) short short8;

__device__ inline unsigned short f2bf(float f) {
    union { float f; unsigned int u; } v; v.f = f;
    unsigned int u = v.u;
    return (unsigned short)((u + 0x7fffu + ((u >> 16) & 1u)) >> 16);
}
__device__ inline float bf2f(unsigned short h) {
    union { unsigned int u; float f; } v; v.u = ((unsigned int)h) << 16; return v.f;
}
__device__ inline float bflo(unsigned int p) {
    union { unsigned int u; float f; } v; v.u = p << 16; return v.f;
}
__device__ inline float bfhi(unsigned int p) {
    union { unsigned int u; float f; } v; v.u = p & 0xffff0000u; return v.f;
}
__device__ inline unsigned int packbf(float a, float b) {
    return (unsigned int)f2bf(a) | ((unsigned int)f2bf(b) << 16);
}

#define EPT 4096   // edges per chunk for range-partitioned passes

// ---------------- fp32 -> bf16 cast ----------------

__global__ __launch_bounds__(256) void cast_k(const float* __restrict__ x, unsigned short* __restrict__ y, int n4) {
    int i = blockIdx.x * 256 + threadIdx.x;
    if (i >= n4) return;
    f32x4 v = ((const f32x4*)x)[i];
    uint2 o; o.x = packbf(v[0], v[1]); o.y = packbf(v[2], v[3]);
    ((uint2*)y)[i] = o;
}

// ---------------- degree + rank (single pass; rank write is coalesced) ----------------
// rank[i] = arrival order of edge i among edges sharing dst[i]. This is the ONLY
// atomic pass: scatter reuses rank instead of a second cursor fetch-add.

__global__ __launch_bounds__(256) void deg_rank_k(const int* __restrict__ dst, int* __restrict__ deg,
                                                  int* __restrict__ rank, int e) {
    int i = blockIdx.x * 256 + threadIdx.x;
    if (i < e) rank[i] = atomicAdd(&deg[dst[i]], 1);
}

__global__ __launch_bounds__(256) void partial_k(const int* __restrict__ deg, int* __restrict__ part, int n) {
    __shared__ int sm[256];
    int t = threadIdx.x;
    int base = blockIdx.x * 1024 + t * 4;
    int s = 0;
#pragma unroll
    for (int j = 0; j < 4; ++j) { int idx = base + j; if (idx < n) s += deg[idx]; }
    sm[t] = s;
    __syncthreads();
    for (int off = 128; off > 0; off >>= 1) {
        if (t < off) sm[t] += sm[t + off];
        __syncthreads();
    }
    if (t == 0) part[blockIdx.x] = sm[0];
}

__global__ __launch_bounds__(256) void scanpart_k(int* __restrict__ part, int nb) {
    __shared__ int sm[256];
    int t = threadIdx.x;
    int v = (t < nb) ? part[t] : 0;
    sm[t] = v;
    __syncthreads();
    for (int off = 1; off < 256; off <<= 1) {
        int u = (t >= off) ? sm[t - off] : 0;
        __syncthreads();
        sm[t] += u;
        __syncthreads();
    }
    if (t < nb) part[t] = sm[t] - v;   // exclusive
}

__global__ __launch_bounds__(256) void rowptr_k(const int* __restrict__ deg, const int* __restrict__ part,
                                                int* __restrict__ rowptr, float* __restrict__ dinv, int n) {
    __shared__ int sm[256];
    int t = threadIdx.x;
    int base = blockIdx.x * 1024 + t * 4;
    int d[4]; int s = 0;
#pragma unroll
    for (int j = 0; j < 4; ++j) { int idx = base + j; d[j] = (idx < n) ? deg[idx] : 0; s += d[j]; }
    sm[t] = s;
    __syncthreads();
    for (int off = 1; off < 256; off <<= 1) {
        int u = (t >= off) ? sm[t - off] : 0;
        __syncthreads();
        sm[t] += u;
        __syncthreads();
    }
    int ex = part[blockIdx.x] + sm[t] - s;
#pragma unroll
    for (int j = 0; j < 4; ++j) {
        int idx = base + j;
        if (idx < n) {
            rowptr[idx] = ex;
            dinv[idx] = rsqrtf(fmaxf((float)d[j], 1.0f));
        }
        ex += d[j];
    }
    if (blockIdx.x == gridDim.x - 1 && t == 255) rowptr[n] = part[blockIdx.x] + sm[255];
}

// rank-based scatter: zero atomics; 8-range passes keep csrc writes XCD-local.
__global__ __launch_bounds__(256) void scatter8r_k(const int* __restrict__ src, const int* __restrict__ dst,
                                                   const int* __restrict__ rowptr, const int* __restrict__ rank,
                                                   int* __restrict__ csrc, int e, int n, int n8) {
    int r = blockIdx.x & 7;
    int chunk = blockIdx.x >> 3;
    int base = chunk * EPT;
    int lim = base + EPT; if (lim > e) lim = e;
    int lo = r * n8;
    int hi = lo + n8; if (hi > n) hi = n;
    for (int i = base + threadIdx.x; i < lim; i += 256) {
        int d = dst[i];
        if (d >= lo && d < hi) {
            csrc[rowptr[d] + rank[i]] = src[i];
        }
    }
}

// ---------------- SpMM (normalized adjacency), bf16 rows, CSR by dst ----------------

template<bool AFF>
__global__ __launch_bounds__(256) void spmm_bf_k(const unsigned short* __restrict__ x, const int* __restrict__ rowptr,
                                                 const int* __restrict__ csrc, const float* __restrict__ dinv,
                                                 const float* __restrict__ gscale, const float* __restrict__ goff,
                                                 unsigned short* __restrict__ out, int n) {
    int lane = threadIdx.x & 63;
    int wave = threadIdx.x >> 6;
    int node = blockIdx.x * 4 + wave;
    if (node >= n) return;
    int g = lane >> 4;        // edge group 0..3
    int c = lane & 15;        // uint4 column index: bf16 cols c*8 .. c*8+7
    int beg = rowptr[node], end = rowptr[node + 1];
    float acc[8];
    float sw = 0.f;
#pragma unroll
    for (int j = 0; j < 8; ++j) acc[j] = 0.f;

    int i = beg + g;
    for (; i + 12 < end; i += 16) {
        int s0 = csrc[i], s1 = csrc[i + 4], s2 = csrc[i + 8], s3 = csrc[i + 12];
        float w0 = dinv[s0], w1 = dinv[s1], w2 = dinv[s2], w3 = dinv[s3];
        uint4 v0 = ((const uint4*)(x + (size_t)s0 * 128))[c];
        uint4 v1 = ((const uint4*)(x + (size_t)s1 * 128))[c];
        uint4 v2 = ((const uint4*)(x + (size_t)s2 * 128))[c];
        uint4 v3 = ((const uint4*)(x + (size_t)s3 * 128))[c];
        if (AFF) sw += w0 + w1 + w2 + w3;
        acc[0] += w0 * bflo(v0.x); acc[1] += w0 * bfhi(v0.x);
        acc[2] += w0 * bflo(v0.y); acc[3] += w0 * bfhi(v0.y);
        acc[4] += w0 * bflo(v0.z); acc[5] += w0 * bfhi(v0.z);
        acc[6] += w0 * bflo(v0.w); acc[7] += w0 * bfhi(v0.w);
        acc[0] += w1 * bflo(v1.x); acc[1] += w1 * bfhi(v1.x);
        acc[2] += w1 * bflo(v1.y); acc[3] += w1 * bfhi(v1.y);
        acc[4] += w1 * bflo(v1.z); acc[5] += w1 * bfhi(v1.z);
        acc[6] += w1 * bflo(v1.w); acc[7] += w1 * bfhi(v1.w);
        acc[0] += w2 * bflo(v2.x); acc[1] += w2 * bfhi(v2.x);
        acc[2] += w2 * bflo(v2.y); acc[3] += w2 * bfhi(v2.y);
        acc[4] += w2 * bflo(v2.z); acc[5] += w2 * bfhi(v2.z);
        acc[6] += w2 * bflo(v2.w); acc[7] += w2 * bfhi(v2.w);
        acc[0] += w3 * bflo(v3.x); acc[1] += w3 * bfhi(v3.x);
        acc[2] += w3 * bflo(v3.y); acc[3] += w3 * bfhi(v3.y);
        acc[4] += w3 * bflo(v3.z); acc[5] += w3 * bfhi(v3.z);
        acc[6] += w3 * bflo(v3.w); acc[7] += w3 * bfhi(v3.w);
    }
    for (; i < end; i += 4) {
        int s0 = csrc[i];
        float w0 = dinv[s0];
        uint4 v0 = ((const uint4*)(x + (size_t)s0 * 128))[c];
        if (AFF) sw += w0;
        acc[0] += w0 * bflo(v0.x); acc[1] += w0 * bfhi(v0.x);
        acc[2] += w0 * bflo(v0.y); acc[3] += w0 * bfhi(v0.y);
        acc[4] += w0 * bflo(v0.z); acc[5] += w0 * bfhi(v0.z);
        acc[6] += w0 * bflo(v0.w); acc[7] += w0 * bfhi(v0.w);
    }

#pragma unroll
    for (int j = 0; j < 8; ++j) {
        acc[j] += __shfl_xor(acc[j], 16, 64);
        acc[j] += __shfl_xor(acc[j], 32, 64);
    }
    if (AFF) {
        sw += __shfl_xor(sw, 16, 64);
        sw += __shfl_xor(sw, 32, 64);
    }

    float dd = dinv[node];
    if (g == 0) {
        if (AFF) {
            f32x4 sc0 = ((const f32x4*)(gscale + c * 8))[0];
            f32x4 sc1 = ((const f32x4*)(gscale + c * 8))[1];
            f32x4 of0 = ((const f32x4*)(goff + c * 8))[0];
            f32x4 of1 = ((const f32x4*)(goff + c * 8))[1];
#pragma unroll
            for (int j = 0; j < 4; ++j) {
                acc[j] = sc0[j] * acc[j] + of0[j] * sw;
                acc[4 + j] = sc1[j] * acc[4 + j] + of1[j] * sw;
            }
        }
        uint4 o;
        o.x = packbf(acc[0] * dd, acc[1] * dd);
        o.y = packbf(acc[2] * dd, acc[3] * dd);
        o.z = packbf(acc[4] * dd, acc[5] * dd);
        o.w = packbf(acc[6] * dd, acc[7] * dd);
        ((uint4*)(out + (size_t)node * 128))[c] = o;
    }
}

// ---------------- weight packs (all 5 in one launch) ----------------

__device__ inline void pack_one(const float* __restrict__ W, unsigned short* __restrict__ out,
                                int K, int N, int cheb, int id) {
    int total = (K / 32) * (N / 16) * 64;
    if (id >= total) return;
    int lane = id & 63;
    int t2 = id >> 6;
    int nf = N / 16;
    int f = t2 % nf;
    int ks = t2 / nf;
    int col = f * 16 + (lane & 15);
    int kbase = ks * 32 + ((lane >> 4) * 8);
    for (int j = 0; j < 8; ++j) {
        int kg = kbase + j;
        float v;
        if (cheb) {
            int t = kg >> 7, kk = kg & 127;
            float w0 = W[kk * 128 + col], wb = W[16384 + kk * 128 + col], wc = W[32768 + kk * 128 + col];
            v = (t == 0) ? (w0 - wc) : (t == 1) ? (-wb) : (2.0f * wc);
        } else {
            v = W[(size_t)kg * N + col];
        }
        out[(size_t)id * 8 + j] = f2bf(v);
    }
}

__global__ __launch_bounds__(256) void pack_all_k(const float* W1, unsigned short* wp1,
                                                  const float* W2, unsigned short* wp2,
                                                  const float* W3, unsigned short* wp3,
                                                  const float* mw1, unsigned short* wpm1,
                                                  const float* mw2, unsigned short* wpm2) {
    int b = blockIdx.x, t = threadIdx.x;
    if (b < 24)       pack_one(W1, wp1, 384, 128, 1, b * 256 + t);
    else if (b < 48)  pack_one(W2, wp2, 384, 128, 1, (b - 24) * 256 + t);
    else if (b < 72)  pack_one(W3, wp3, 384, 128, 1, (b - 48) * 256 + t);
    else if (b < 80)  pack_one(mw1, wpm1, 128, 128, 0, (b - 72) * 256 + t);
    else              pack_one(mw2, wpm2, 128, 64, 0, (b - 80) * 256 + t);
}

// ---------------- BN coefficients from fused stats ----------------

__global__ __launch_bounds__(128) void bn_coef_k(const float* __restrict__ gsum, const float* __restrict__ gsqs,
                                                 const float* __restrict__ gamma, const float* __restrict__ beta,
                                                 float* __restrict__ gscale, float* __restrict__ goff, float inv_n) {
    int c = threadIdx.x;
    float mu = gsum[c] * inv_n;
    float var = gsqs[c] * inv_n - mu * mu;
    float sc = rsqrtf(var + 1e-5f) * gamma[c];
    gscale[c] = sc;
    goff[c] = beta[c] - mu * sc;
}

// ---------------- MFMA GEMM: 512 threads / 128 rows, LDS-staged B ----------------
// (unchanged from R11 — proven below top-5)

template<bool RELU, bool RES, bool STATS, bool AFFA, bool MLP>
__global__ __launch_bounds__(512, 4) void gemm_k(const unsigned short* __restrict__ s0,
                                                 const unsigned short* __restrict__ s1,
                                                 const unsigned short* __restrict__ s2,
                                                 const unsigned short* __restrict__ wp,
                                                 const float* __restrict__ bias,
                                                 const unsigned short* __restrict__ resid,
                                                 const float* __restrict__ gscale,
                                                 const float* __restrict__ goff,
                                                 float* __restrict__ gsum, float* __restrict__ gsqs,
                                                 unsigned short* __restrict__ outp,
                                                 const unsigned short* __restrict__ wpm1,
                                                 const float* __restrict__ mb1,
                                                 const unsigned short* __restrict__ wpm2,
                                                 const float* __restrict__ mb2,
                                                 float* __restrict__ outf, int n) {
    __shared__ char blds[49152];                  // one 48KB half of Wpack / later wpm1+wpm2
    __shared__ char tl[MLP ? 32768 : 16];         // MLP: 128x128 bf16 t-tile
    __shared__ float bs[STATS ? 128 : 1], bq[STATS ? 128 : 1];
    int t = threadIdx.x;
    int lane = t & 63;
    int wave = t >> 6;                            // 0..7
    int row0 = blockIdx.x * 128;

    if (STATS && t < 128) { bs[t] = 0.f; bq[t] = 0.f; }

    int rowA = row0 + wave * 16 + (lane & 15);
    if (rowA >= n) rowA = n - 1;
    int kg = (lane >> 4) * 8;
    int colb = lane & 15;

    // ---- issue first B-half staging (48KB; 6KB per wave)
    {
        const char* gsrc = (const char*)wp;
        int wbase = wave * 6144;
#pragma unroll
        for (int j = 0; j < 6; ++j) {
            int off = wbase + j * 1024;
            __builtin_amdgcn_global_load_lds((const unsigned int*)(gsrc + off + lane * 16),
                                             (unsigned int*)(blds + off), 16, 0, 0);
        }
    }

    // ---- preload ALL 12 A-frags; keep-alive pins the loads here
    short8 a[12];
#pragma unroll
    for (int ks = 0; ks < 12; ++ks) {
        const unsigned short* sp = (ks < 4) ? s0 : ((ks < 8) ? s1 : s2);
        int kk = (ks & 3) * 32 + kg;
        a[ks] = *(const short8*)(sp + (size_t)rowA * 128 + kk);
    }
    if (AFFA) {
#pragma unroll
        for (int ks = 0; ks < 4; ++ks) {
            int kk = ks * 32 + kg;
            union { unsigned short u[8]; short8 v; } af;
#pragma unroll
            for (int j = 0; j < 8; ++j) {
                float xv = bf2f((unsigned short)a[ks][j]);
                af.u[j] = f2bf(xv * gscale[kk + j] + goff[kk + j]);
            }
            a[ks] = af.v;
        }
    }
#pragma unroll
    for (int ks = 0; ks < 12; ++ks) {
        f32x4 kv = *(f32x4*)&a[ks];
        asm volatile("" :: "v"(kv));   // force materialization before the barrier
    }

    f32x4 acc[8];
#pragma unroll
    for (int f = 0; f < 8; ++f) acc[f] = (f32x4)(0.0f);

#pragma unroll
    for (int half = 0; half < 2; ++half) {
        __syncthreads();   // drains vmcnt: staged B-half ready

#pragma unroll
        for (int ks6 = 0; ks6 < 6; ++ks6) {
            int ks = half * 6 + ks6;
#pragma unroll
            for (int f = 0; f < 8; ++f) {
                short8 bb = *(const short8*)(blds + (ks6 * 8 + f) * 1024 + lane * 16);
                acc[f] = __builtin_amdgcn_mfma_f32_16x16x32_bf16(a[ks], bb, acc[f], 0, 0, 0);
            }
        }

        if (half == 0) {
            __syncthreads();   // all waves done reading half 0
            const char* gsrc = (const char*)wp + 49152;
            int wbase = wave * 6144;
#pragma unroll
            for (int j = 0; j < 6; ++j) {
                int off = wbase + j * 1024;
                __builtin_amdgcn_global_load_lds((const unsigned int*)(gsrc + off + lane * 16),
                                                 (unsigned int*)(blds + off), 16, 0, 0);
            }
        }
    }

    // ---- epilogue: v = relu(acc+bias) [+ resid]
    int rowD = row0 + wave * 16 + ((lane >> 4) << 2);
    int lrowD = wave * 16 + ((lane >> 4) << 2);
#pragma unroll
    for (int f = 0; f < 8; ++f) {
        int c = f * 16 + colb;
        float bv = bias[c];
        float ls = 0.f, lq = 0.f;
#pragma unroll
        for (int r = 0; r < 4; ++r) {
            int row = rowD + r;
            if (row >= n) continue;
            float v = acc[f][r] + bv;
            if (RELU) v = fmaxf(v, 0.0f);
            if (RES) v += bf2f(resid[(size_t)row * 128 + c]);
            if (STATS) { ls += v; lq += v * v; }
            if (MLP) {
                int lrow = lrowD + r;
                int byte = lrow * 256 + c * 2;
                byte ^= ((lrow & 7) << 4);
                *(unsigned short*)(tl + byte) = f2bf(v);
            } else {
                outp[(size_t)row * 128 + c] = f2bf(v);
            }
        }
        if (STATS) { atomicAdd(&bs[c], ls); atomicAdd(&bq[c], lq); }
    }

    if (STATS) {
        __syncthreads();
        if (t < 128) {
            atomicAdd(&gsum[t], bs[t]);
            atomicAdd(&gsqs[t], bq[t]);
        }
    }

    if (MLP) {
        __syncthreads();   // t-tile complete; blds reads complete
        // restage blds with wpm1 (32KB) + wpm2 (16KB)
        {
            int wbase = wave * 6144;
#pragma unroll
            for (int j = 0; j < 6; ++j) {
                int off = wbase + j * 1024;
                const char* g = (off < 32768) ? ((const char*)wpm1 + off)
                                              : ((const char*)wpm2 + (off - 32768));
                __builtin_amdgcn_global_load_lds((const unsigned int*)(g + lane * 16),
                                                 (unsigned int*)(blds + off), 16, 0, 0);
            }
        }
        __syncthreads();   // drains vmcnt

        // GEMM1: t2 = relu(y@mw1 + mb1)
        int lrowA = wave * 16 + (lane & 15);
        f32x4 acc2[8];
#pragma unroll
        for (int f = 0; f < 8; ++f) acc2[f] = (f32x4)(0.0f);
#pragma unroll
        for (int ks = 0; ks < 4; ++ks) {
            int byte = lrowA * 256 + (ks * 32 + kg) * 2;
            byte ^= ((lrowA & 7) << 4);
            short8 av = *(const short8*)(tl + byte);
#pragma unroll
            for (int f = 0; f < 8; ++f) {
                short8 b = *(const short8*)(blds + (ks * 8 + f) * 1024 + lane * 16);
                acc2[f] = __builtin_amdgcn_mfma_f32_16x16x32_bf16(av, b, acc2[f], 0, 0, 0);
            }
        }
        __syncthreads();   // all t-tile reads done before overwrite

#pragma unroll
        for (int f = 0; f < 8; ++f) {
            int c = f * 16 + colb;
            float bv = mb1[c];
#pragma unroll
            for (int r = 0; r < 4; ++r) {
                int lrow = lrowD + r;
                float v = fmaxf(acc2[f][r] + bv, 0.0f);
                int byte = lrow * 256 + c * 2;
                byte ^= ((lrow & 7) << 4);
                *(unsigned short*)(tl + byte) = f2bf(v);
            }
        }
        __syncthreads();

        // GEMM2: out = t2@mw2 + mb2 (N=64, fp32)
        f32x4 acc3[4];
#pragma unroll
        for (int f = 0; f < 4; ++f) acc3[f] = (f32x4)(0.0f);
#pragma unroll
        for (int ks = 0; ks < 4; ++ks) {
            int byte = lrowA * 256 + (ks * 32 + kg) * 2;
            byte ^= ((lrowA & 7) << 4);
            short8 av = *(const short8*)(tl + byte);
#pragma unroll
            for (int f = 0; f < 4; ++f) {
                short8 b = *(const short8*)(blds + 32768 + (ks * 4 + f) * 1024 + lane * 16);
                acc3[f] = __builtin_amdgcn_mfma_f32_16x16x32_bf16(av, b, acc3[f], 0, 0, 0);
            }
        }
#pragma unroll
        for (int f = 0; f < 4; ++f) {
            int c = f * 16 + colb;
            float bv = mb2[c];
#pragma unroll
            for (int r = 0; r < 4; ++r) {
                int row = rowD + r;
                if (row >= n) continue;
                outf[(size_t)row * 64 + c] = acc3[f][r] + bv;
            }
        }
    }
}

// ---------------- launch ----------------

extern "C" void kernel_launch(void* const* d_in, const int* in_sizes, int n_in,
                              void* d_out, int out_size, void* d_ws, size_t ws_size,
                              hipStream_t stream) {
    const float* feat  = (const float*)d_in[0];
    const int*   src   = (const int*)d_in[1];
    const int*   dst   = (const int*)d_in[2];
    const float* W1    = (const float*)d_in[3];
    const float* b1    = (const float*)d_in[4];
    const float* W2    = (const float*)d_in[5];
    const float* b2    = (const float*)d_in[6];
    const float* W3    = (const float*)d_in[7];
    const float* b3    = (const float*)d_in[8];
    const float* gamma = (const float*)d_in[9];
    const float* beta  = (const float*)d_in[10];
    const float* mw1   = (const float*)d_in[11];
    const float* mb1   = (const float*)d_in[12];
    const float* mw2   = (const float*)d_in[13];
    const float* mb2   = (const float*)d_in[14];
    float* outp = (float*)d_out;

    const int n = in_sizes[0] / 128;
    const int e = in_sizes[1];
    const int n8 = (n + 7) / 8;

    char* w = (char*)d_ws;
    auto alloc = [&](size_t bytes) -> void* {
        void* p = (void*)w;
        w += (bytes + 255) & ~(size_t)255;
        return p;
    };
    unsigned short* featb = (unsigned short*)alloc((size_t)n * 128 * 2);
    unsigned short* buf0  = (unsigned short*)alloc((size_t)n * 128 * 2);
    unsigned short* buf1  = (unsigned short*)alloc((size_t)n * 128 * 2);
    unsigned short* buf2  = (unsigned short*)alloc((size_t)n * 128 * 2);
    unsigned short* buf3  = (unsigned short*)alloc((size_t)n * 128 * 2);
    int*   deg    = (int*)alloc((size_t)n * 4);
    float* dinv   = (float*)alloc((size_t)n * 4);
    int*   rowptr = (int*)alloc((size_t)(n + 1) * 4);
    int*   rank   = (int*)alloc((size_t)e * 4);
    int*   csrc   = (int*)alloc((size_t)e * 4);
    int*   part   = (int*)alloc(256 * 4);
    unsigned short* wp1  = (unsigned short*)alloc(12 * 8 * 512 * 2);
    unsigned short* wp2  = (unsigned short*)alloc(12 * 8 * 512 * 2);
    unsigned short* wp3  = (unsigned short*)alloc(12 * 8 * 512 * 2);
    unsigned short* wpm1 = (unsigned short*)alloc(4 * 8 * 512 * 2);
    unsigned short* wpm2 = (unsigned short*)alloc(4 * 4 * 512 * 2);
    float* gsum   = (float*)alloc(128 * 4);   // adjacent: one 1KB memset covers
    float* gsqs   = (float*)alloc(128 * 4);
    float* gscale = (float*)alloc(128 * 4);
    float* goff   = (float*)alloc(128 * 4);

    const int gGemm = (n + 127) / 128;
    const int gSpmm = (n + 3) / 4;
    const int nb = (n + 1023) / 1024;
    const int gE  = (e + 255) / 256;
    const int gE8 = 8 * ((e + EPT - 1) / EPT);

    // prep
    cast_k<<<(n * 32 + 255) / 256, 256, 0, stream>>>(feat, featb, n * 32);
    hipMemsetAsync(deg, 0, (size_t)n * 4, stream);
    hipMemsetAsync(gsum, 0, 1024, stream);   // gsum+gsqs (256-aligned adjacent)
    deg_rank_k<<<gE, 256, 0, stream>>>(dst, deg, rank, e);
    partial_k<<<nb, 256, 0, stream>>>(deg, part, n);
    scanpart_k<<<1, 256, 0, stream>>>(part, nb);
    rowptr_k<<<nb, 256, 0, stream>>>(deg, part, rowptr, dinv, n);
    scatter8r_k<<<gE8, 256, 0, stream>>>(src, dst, rowptr, rank, csrc, e, n, n8);
    pack_all_k<<<84, 256, 0, stream>>>(W1, wp1, W2, wp2, W3, wp3, mw1, wpm1, mw2, wpm2);

    // Layer 1: cheb(features, W1) -> relu -> buf0 (pre-BN), fused BN stats
    spmm_bf_k<false><<<gSpmm, 256, 0, stream>>>(featb, rowptr, csrc, dinv, nullptr, nullptr, buf1, n);
    spmm_bf_k<false><<<gSpmm, 256, 0, stream>>>(buf1, rowptr, csrc, dinv, nullptr, nullptr, buf2, n);
    gemm_k<true, false, true, false, false><<<gGemm, 512, 0, stream>>>(
        featb, buf1, buf2, wp1, b1, nullptr, nullptr, nullptr, gsum, gsqs, buf0,
        nullptr, nullptr, nullptr, nullptr, nullptr, n);
    bn_coef_k<<<1, 128, 0, stream>>>(gsum, gsqs, gamma, beta, gscale, goff, 1.0f / (float)n);

    // Layer 2a: cheb(BN(buf0), W2) -> relu -> buf3  (BN fused into consumers)
    spmm_bf_k<true><<<gSpmm, 256, 0, stream>>>(buf0, rowptr, csrc, dinv, gscale, goff, buf1, n);
    spmm_bf_k<false><<<gSpmm, 256, 0, stream>>>(buf1, rowptr, csrc, dinv, nullptr, nullptr, buf2, n);
    gemm_k<true, false, false, true, false><<<gGemm, 512, 0, stream>>>(
        buf0, buf1, buf2, wp2, b2, nullptr, gscale, goff, nullptr, nullptr, buf3,
        nullptr, nullptr, nullptr, nullptr, nullptr, n);

    // Layer 2b: cheb(buf3, W2) -> relu -> buf0
    spmm_bf_k<false><<<gSpmm, 256, 0, stream>>>(buf3, rowptr, csrc, dinv, nullptr, nullptr, buf1, n);
    spmm_bf_k<false><<<gSpmm, 256, 0, stream>>>(buf1, rowptr, csrc, dinv, nullptr, nullptr, buf2, n);
    gemm_k<true, false, false, false, false><<<gGemm, 512, 0, stream>>>(
        buf3, buf1, buf2, wp2, b2, nullptr, nullptr, nullptr, nullptr, nullptr, buf0,
        nullptr, nullptr, nullptr, nullptr, nullptr, n);

    // Layer 3 + MLP fused: out = relu(relu(cheb)+resid @ mw1+mb1)@mw2 + mb2
    spmm_bf_k<false><<<gSpmm, 256, 0, stream>>>(buf0, rowptr, csrc, dinv, nullptr, nullptr, buf1, n);
    spmm_bf_k<false><<<gSpmm, 256, 0, stream>>>(buf1, rowptr, csrc, dinv, nullptr, nullptr, buf2, n);
    gemm_k<true, true, false, false, true><<<gGemm, 512, 0, stream>>>(
        buf0, buf1, buf2, wp3, b3, buf0, nullptr, nullptr, nullptr, nullptr, nullptr,
        wpm1, mb1, wpm2, mb2, outp, n);
}